// Round 8
// baseline (482.682 us; speedup 1.0000x reference)
//
#include <hip/hip_runtime.h>
#include <math.h>

#define B_SZ   2048
#define F_SZ   12288
#define D_SZ   512
#define N_LK   100000
#define N_PAD  100096
#define NTILES 391          // N_PAD / 256
#define NGRP   32           // persistent groups along nt (256 blocks = 8 mt x 32 grp)
#define JMAX   13

typedef __attribute__((ext_vector_type(8))) short bf16x8;
typedef __attribute__((ext_vector_type(8))) unsigned short ushort8;
typedef __attribute__((ext_vector_type(4))) float f32x4;
typedef __attribute__((ext_vector_type(16))) float f32x16;
typedef __attribute__((ext_vector_type(8))) int i32x8;

__device__ __forceinline__ unsigned short f2bf(float f) {
  union { float f; unsigned u; } v; v.f = f;
  unsigned r = v.u + 0x7FFFu + ((v.u >> 16) & 1u);
  return (unsigned short)(r >> 16);
}

// f32 -> OCP e4m3fn, round-nearest-even, software (deterministic, no hw-cvt dependency)
__device__ __forceinline__ unsigned char f2fp8(float f) {
  union { float f; unsigned u; } v; v.f = f;
  unsigned s = (v.u >> 24) & 0x80u;
  unsigned a = v.u & 0x7FFFFFFFu;
  if (a >= 0x43E00000u) return (unsigned char)(s | 0x7E);  // |x|>=448 (or NaN) -> clamp
  int e32 = (int)(a >> 23) - 127;
  if (e32 < -10) return (unsigned char)s;                  // rounds to zero
  unsigned m24 = (a & 0x7FFFFFu) | 0x800000u;
  int shift = (e32 >= -6) ? 20 : (14 - e32);               // subnormal unit 2^-9
  if (shift > 24) return (unsigned char)s;
  unsigned keep = m24 >> shift;
  unsigned rem = m24 & ((1u << shift) - 1u);
  unsigned half = 1u << (shift - 1);
  keep += (rem > half || (rem == half && (keep & 1u))) ? 1u : 0u;
  if (e32 >= -6) {
    if (keep == 16u) { keep = 8u; ++e32; }
    return (unsigned char)(s | ((unsigned)(e32 + 7) << 3) | (keep & 7u));
  }
  if (keep >= 8u) return (unsigned char)(s | 0x08u);       // rounded up to 2^-6
  return (unsigned char)(s | keep);
}

#define GLOAD16(gp, lp) __builtin_amdgcn_global_load_lds( \
    (__attribute__((address_space(1))) void*)(gp),        \
    (__attribute__((address_space(3))) void*)(lp), 16, 0, 0)

#define VMCNT(n) asm volatile("s_waitcnt vmcnt(" #n ")" ::: "memory")
#define BARRIER __builtin_amdgcn_s_barrier()
#define LGKM0 do { asm volatile("s_waitcnt lgkmcnt(0)" ::: "memory"); \
                   __builtin_amdgcn_sched_barrier(0); } while (0)

// scaled MX MFMA: fmt fp8(e4m3) for A and B; scale bytes all 0x7F = 2^0 = 1.0
// (every byte 127 so the op_sel byte choice is irrelevant)
#define MFMAS(A, B, C) __builtin_amdgcn_mfma_scale_f32_32x32x64_f8f6f4( \
    (A), (B), (C), 0, 0, 0, 0x7F7F7F7F, 0, 0x7F7F7F7F)

__device__ __forceinline__ i32x8 ldfrag(const char* base, int o0, int o1) {
  int4 lo = *(const int4*)(base + o0);
  int4 hi = *(const int4*)(base + o1);
  i32x8 r = {lo.x, lo.y, lo.z, lo.w, hi.x, hi.y, hi.z, hi.w};
  return r;
}

// ---------------- merged prep: conv_mse | transpose_w | conv_lookup(fp8) | zero embf ----
#define PREP_MSE_BLKS   2048
#define PREP_TW_BLKS    1536   // 192 x 8 tiles of 64x64
#define PREP_LK_BLKS    (N_PAD / 4)
#define PREP_ZERO_BLKS  512
#define PREP_TOTAL (PREP_MSE_BLKS + PREP_TW_BLKS + PREP_LK_BLKS + PREP_ZERO_BLKS)

__global__ __launch_bounds__(256) void prep_k(
    const float* __restrict__ x, const float* __restrict__ y,
    unsigned short* __restrict__ xb, float* __restrict__ part,
    const float* __restrict__ W, unsigned short* __restrict__ Wt,
    const float* __restrict__ lk, unsigned char* __restrict__ lb,
    float* __restrict__ lsq, float* __restrict__ embf) {
  __shared__ float tl[64][65];
  const int bx = blockIdx.x;
  const int tid = threadIdx.x;

  if (bx < PREP_MSE_BLKS) {
    const long n8 = (long)B_SZ * F_SZ / 8;
    long i = (long)bx * 256 + tid;
    const long stride = (long)PREP_MSE_BLKS * 256;
    float s = 0.f;
    for (; i < n8; i += stride) {
      const float4* px = (const float4*)(x + i * 8);
      const float4* py = (const float4*)(y + i * 8);
      float4 a = px[0], b = px[1];
      float4 c = py[0], d = py[1];
      ushort8 o;
      o[0] = f2bf(a.x); o[1] = f2bf(a.y); o[2] = f2bf(a.z); o[3] = f2bf(a.w);
      o[4] = f2bf(b.x); o[5] = f2bf(b.y); o[6] = f2bf(b.z); o[7] = f2bf(b.w);
      *(ushort8*)(xb + i * 8) = o;
      float t0 = a.x - c.x, t1 = a.y - c.y, t2 = a.z - c.z, t3 = a.w - c.w;
      float t4 = b.x - d.x, t5 = b.y - d.y, t6 = b.z - d.z, t7 = b.w - d.w;
      s += t0 * t0 + t1 * t1 + t2 * t2 + t3 * t3;
      s += t4 * t4 + t5 * t5 + t6 * t6 + t7 * t7;
    }
#pragma unroll
    for (int off = 1; off < 64; off <<= 1) s += __shfl_xor(s, off);
    if ((tid & 63) == 0) tl[0][tid >> 6] = s;
    __syncthreads();
    if (tid == 0) part[bx] = tl[0][0] + tl[0][1] + tl[0][2] + tl[0][3];
  } else if (bx < PREP_MSE_BLKS + PREP_TW_BLKS) {
    const int b = bx - PREP_MSE_BLKS;
    const int r0 = (b % 192) * 64;  // F dim
    const int c0 = (b / 192) * 64;  // D dim
#pragma unroll
    for (int p = 0; p < 16; ++p) {
      int idx = p * 256 + tid;
      int r = idx >> 6, c = idx & 63;
      tl[c][r] = W[(size_t)(r0 + r) * D_SZ + c0 + c];
    }
    __syncthreads();
#pragma unroll
    for (int p = 0; p < 2; ++p) {
      int chunk = p * 256 + tid;
      int rr = chunk >> 3, cc = (chunk & 7) * 8;
      ushort8 o;
#pragma unroll
      for (int j = 0; j < 8; ++j) o[j] = f2bf(tl[rr][cc + j]);
      *(ushort8*)&Wt[(size_t)(c0 + rr) * F_SZ + r0 + cc] = o;
    }
  } else if (bx < PREP_MSE_BLKS + PREP_TW_BLKS + PREP_LK_BLKS) {
    // lookup f32 -> fp8 e4m3 (padded) + per-row sumsq (f32, unrounded — hinge slack)
    const int n = (bx - PREP_MSE_BLKS - PREP_TW_BLKS) * 4 + (tid >> 6);
    const int t = tid & 63;
    unsigned lo = 0, hi = 0;
    float s = 0.f;
    if (n < N_LK) {
      const float4* row = (const float4*)(lk + (size_t)n * D_SZ);
      float4 a = row[t * 2], b = row[t * 2 + 1];
      float v[8] = {a.x, a.y, a.z, a.w, b.x, b.y, b.z, b.w};
#pragma unroll
      for (int j = 0; j < 4; ++j) lo |= (unsigned)f2fp8(v[j]) << (8 * j);
#pragma unroll
      for (int j = 0; j < 4; ++j) hi |= (unsigned)f2fp8(v[j + 4]) << (8 * j);
#pragma unroll
      for (int j = 0; j < 8; ++j) s += v[j] * v[j];
    }
    uint2 o2; o2.x = lo; o2.y = hi;
    *(uint2*)&lb[(size_t)n * D_SZ + t * 8] = o2;
#pragma unroll
    for (int off = 1; off < 64; off <<= 1) s += __shfl_xor(s, off);
    if (t == 0) lsq[n] = (n < N_LK) ? s : 1e30f;
  } else {
    long i = (long)(bx - PREP_MSE_BLKS - PREP_TW_BLKS - PREP_LK_BLKS) * 256 + tid;
    const long n4 = (long)B_SZ * D_SZ / 4;
    const long stride = (long)PREP_ZERO_BLKS * 256;
    float4 z = {0.f, 0.f, 0.f, 0.f};
    for (; i < n4; i += stride) ((float4*)embf)[i] = z;
  }
}

// ---------------- GEMM-A split-K=12 (bf16, unchanged) ----------------
__global__ __launch_bounds__(256) void gemm_a_sk(const unsigned short* __restrict__ A,
                                                 const unsigned short* __restrict__ Bm,
                                                 float* __restrict__ embf) {
  __shared__ unsigned short lsA[128 * 32];
  __shared__ unsigned short lsB[128 * 32];
  const int tid = threadIdx.x;
  const int bid = blockIdx.x;
  const int mt = bid & 15, dt = (bid >> 4) & 3, ks = bid >> 6;
  const int m0 = mt * 128, n0 = dt * 128;
  const int k0base = ks * 1024;
  const int l = tid & 63;
  const int w = tid >> 6;
  const int wr = (w >> 1) * 64, wc = (w & 1) * 64;
  const int g = l >> 4, lane16 = l & 15;

  const int srow = tid >> 2;
  const int scol = (tid & 3) * 8;
  const unsigned short* Ag0 = A + (size_t)(m0 + srow) * F_SZ + scol + k0base;
  const unsigned short* Ag1 = A + (size_t)(m0 + 64 + srow) * F_SZ + scol + k0base;
  const unsigned short* Bg0 = Bm + (size_t)(n0 + srow) * F_SZ + scol + k0base;
  const unsigned short* Bg1 = Bm + (size_t)(n0 + 64 + srow) * F_SZ + scol + k0base;
  unsigned short* la0 = &lsA[tid * 8];
  unsigned short* la1 = &lsA[2048 + tid * 8];
  unsigned short* lb0 = &lsB[tid * 8];
  unsigned short* lb1 = &lsB[2048 + tid * 8];

  int ar[4], br[4];
#pragma unroll
  for (int m = 0; m < 4; ++m) ar[m] = (wr + m * 16 + lane16) * 32 + g * 8;
#pragma unroll
  for (int n = 0; n < 4; ++n) br[n] = (wc + n * 16 + lane16) * 32 + g * 8;

  f32x4 acc[4][4] = {};

  for (int k0 = 0; k0 < 1024; k0 += 32) {
    GLOAD16(Ag0 + k0, la0);
    GLOAD16(Ag1 + k0, la1);
    GLOAD16(Bg0 + k0, lb0);
    GLOAD16(Bg1 + k0, lb1);
    __syncthreads();
    bf16x8 af[4], bfv[4];
#pragma unroll
    for (int m = 0; m < 4; ++m) af[m] = *(const bf16x8*)&lsA[ar[m]];
#pragma unroll
    for (int n = 0; n < 4; ++n) bfv[n] = *(const bf16x8*)&lsB[br[n]];
#pragma unroll
    for (int m = 0; m < 4; ++m)
#pragma unroll
      for (int n = 0; n < 4; ++n)
        acc[m][n] = __builtin_amdgcn_mfma_f32_16x16x32_bf16(af[m], bfv[n], acc[m][n], 0, 0, 0);
    __syncthreads();
  }
#pragma unroll
  for (int m = 0; m < 4; ++m)
#pragma unroll
    for (int n = 0; n < 4; ++n)
#pragma unroll
      for (int r = 0; r < 4; ++r) {
        int row = m0 + wr + m * 16 + g * 4 + r;
        int col = n0 + wc + n * 16 + lane16;
        atomicAdd(&embf[(size_t)row * D_SZ + col], acc[m][n][r]);
      }
}

// embf f32 -> embq fp8 + per-row esq (f32, unrounded)
__global__ __launch_bounds__(256) void esq_conv_k(const float* __restrict__ embf,
                                                  unsigned char* __restrict__ embq,
                                                  float* __restrict__ esq) {
  int r = blockIdx.x * 4 + (threadIdx.x >> 6);
  int t = threadIdx.x & 63;
  const float4* row = (const float4*)(embf + (size_t)r * D_SZ);
  float4 a = row[t * 2], b = row[t * 2 + 1];
  float v[8] = {a.x, a.y, a.z, a.w, b.x, b.y, b.z, b.w};
  unsigned lo = 0, hi = 0;
  float s = 0.f;
#pragma unroll
  for (int j = 0; j < 4; ++j) lo |= (unsigned)f2fp8(v[j]) << (8 * j);
#pragma unroll
  for (int j = 0; j < 4; ++j) hi |= (unsigned)f2fp8(v[j + 4]) << (8 * j);
#pragma unroll
  for (int j = 0; j < 8; ++j) s += v[j] * v[j];
  uint2 o2; o2.x = lo; o2.y = hi;
  *(uint2*)&embq[(size_t)r * D_SZ + t * 8] = o2;
#pragma unroll
  for (int off = 1; off < 64; off <<= 1) s += __shfl_xor(s, off);
  if (t == 0) esq[r] = s;
}

// ---------------- GEMM-B: persistent fused cdist-min, MX-fp8 32x32x64, 256x256 ----------
// grid 256 (1/CU), 512 threads = 8 waves (2M x 4N), wave tile 128x64,
// acc = f32x16[4][2] (AGPR). BK=64 (one fp8 K-step): A-tile 256x64B = 16KB, B same.
// Ring-4 (128KB) + counted VMCNT(8), 4 loads/tile — R7's proven skeleton.
// mt = bid>>5, grp = bid&31: B-sharing blocks co-start on the same XCD.
// 16B-slot swizzle: data (row,kb) at slot' = (kb>>4) ^ ((row>>1)&3); source pre-swizzled.
// Per-row min folded per nt-tile into LDS u32 atomicMin with order-preserving f32 key.
// lsq preloaded to LDS at prologue (folds never touch vmem -> vmcnt stays clean).
__global__ __launch_bounds__(512, 2) void gemm_min_k(
    const unsigned char* __restrict__ Aq,   // embq [2048][512] fp8
    const unsigned char* __restrict__ Bq,   // lb   [100096][512] fp8
    const float* __restrict__ esq, const float* __restrict__ lsq,
    float* __restrict__ minpart) {          // [NGRP][2048]
  __shared__ char lsA[4 * 16384];
  __shared__ char lsB[4 * 16384];
  __shared__ float lsq_lds[JMAX * 256];
  __shared__ unsigned lmin[256];

  const int tid = threadIdx.x;
  const int grp = blockIdx.x & 31;
  const int mt = blockIdx.x >> 5;      // 0..7
  const int m0 = mt * 256;
  const int J = (NTILES - grp + NGRP - 1) / NGRP;  // 12 or 13
  const int T = J * 8;                             // K-64 steps (8 per nt-tile)

  const int l = tid & 63;
  const int wid = tid >> 6;
  const int wm = wid >> 2;      // 0..1 -> rows wm*128
  const int wn = wid & 3;       // 0..3 -> cols wn*64
  const int hi = l >> 5;
  const int l31 = l & 31;

  // staging source (pre-swizzled 16B slot; (row>>1)&3 == (tid>>3)&3 for both halves)
  const int scol = ((tid & 3) ^ ((tid >> 3) & 3)) * 16;
  const unsigned char* Asrc = Aq + (size_t)(m0 + (tid >> 2)) * D_SZ + scol;
  const unsigned char* Bsrc = Bq + (size_t)(tid >> 2) * D_SZ + scol;

  // fragment ds_read byte offsets (2x b128 per 32B frag, swizzled slots)
  int aro[4][2], bro[2][2];
#pragma unroll
  for (int mf = 0; mf < 4; ++mf) {
    int row = wm * 128 + mf * 32 + l31;
#pragma unroll
    for (int j = 0; j < 2; ++j)
      aro[mf][j] = row * 64 + (((hi * 2 + j) ^ ((row >> 1) & 3)) << 4);
  }
#pragma unroll
  for (int nf = 0; nf < 2; ++nf) {
    int row = wn * 64 + nf * 32 + l31;
#pragma unroll
    for (int j = 0; j < 2; ++j)
      bro[nf][j] = row * 64 + (((hi * 2 + j) ^ ((row >> 1) & 3)) << 4);
  }

  f32x16 acc[4][2] = {};
  const f32x16 fzero = {};

  // prologue: lsq -> LDS, lmin init, then full drain via __syncthreads (vmcnt baseline 0)
  for (int j = 0; j < J; ++j)
    if (tid < 256) lsq_lds[j * 256 + tid] = lsq[(grp + NGRP * j) * 256 + tid];
  if (tid < 256) lmin[tid] = 0xFFFFFFFFu;
  __syncthreads();

  auto stageA = [&](int s, int h) {
    GLOAD16(Asrc + (size_t)h * 128 * D_SZ + (s & 7) * 64,
            lsA + (s & 3) * 16384 + h * 8192 + tid * 16);
  };
  auto stageB = [&](int s, int h) {
    const size_t nrowb = (size_t)(grp + NGRP * (s >> 3)) * 256;
    GLOAD16(Bsrc + (nrowb + (size_t)h * 128) * D_SZ + (s & 7) * 64,
            lsB + (s & 3) * 16384 + h * 8192 + tid * 16);
  };
  auto fold = [&](int j) {
    const int cbase = j * 256 + wn * 64 + l31;
    float lq0 = lsq_lds[cbase];
    float lq1 = lsq_lds[cbase + 32];
#pragma unroll
    for (int mf = 0; mf < 4; ++mf) {
#pragma unroll
      for (int r = 0; r < 16; ++r) {
        float v = fminf(fmaf(-2.f, acc[mf][0][r], lq0), fmaf(-2.f, acc[mf][1][r], lq1));
#pragma unroll
        for (int off = 1; off < 32; off <<= 1) v = fminf(v, __shfl_xor(v, off));
        if (l31 == 0) {
          unsigned u = __float_as_uint(v);
          u = (u & 0x80000000u) ? ~u : (u | 0x80000000u);  // order-preserving key
          atomicMin(&lmin[wm * 128 + mf * 32 + (r & 3) + 8 * (r >> 2) + 4 * hi], u);
        }
      }
#pragma unroll
      for (int nf = 0; nf < 2; ++nf) acc[mf][nf] = fzero;
    }
  };

  // prologue: tiles 0,1,2 in flight (12 loads); retire tile 0
#pragma unroll
  for (int s = 0; s < 3; ++s) {
    stageA(s, 0); stageA(s, 1); stageB(s, 0); stageB(s, 1);
  }
  VMCNT(8);
  BARRIER;

  for (int t = 0; t < T; ++t) {
    const char* pA = lsA + (t & 3) * 16384;
    const char* pB = lsB + (t & 3) * 16384;
    const int s = t + 3;
    const bool stg = s < T;

    // ---- phase 0: bfv0,bfv1,af0,af1 | stage A(t+3) | 4 MFMA (m0,m1) ----
    i32x8 bfv0 = ldfrag(pB, bro[0][0], bro[0][1]);
    i32x8 bfv1 = ldfrag(pB, bro[1][0], bro[1][1]);
    i32x8 af0 = ldfrag(pA, aro[0][0], aro[0][1]);
    i32x8 af1 = ldfrag(pA, aro[1][0], aro[1][1]);
    if (stg) { stageA(s, 0); stageA(s, 1); }
    BARRIER; LGKM0;
    __builtin_amdgcn_s_setprio(1);
    acc[0][0] = MFMAS(af0, bfv0, acc[0][0]);
    acc[0][1] = MFMAS(af0, bfv1, acc[0][1]);
    acc[1][0] = MFMAS(af1, bfv0, acc[1][0]);
    acc[1][1] = MFMAS(af1, bfv1, acc[1][1]);
    __builtin_amdgcn_s_setprio(0);
    BARRIER;

    // ---- phase 1: af2,af3 | stage B(t+3) | 4 MFMA (m2,m3) | fold | vmcnt ----
    af0 = ldfrag(pA, aro[2][0], aro[2][1]);
    af1 = ldfrag(pA, aro[3][0], aro[3][1]);
    if (stg) { stageB(s, 0); stageB(s, 1); }
    BARRIER; LGKM0;
    __builtin_amdgcn_s_setprio(1);
    acc[2][0] = MFMAS(af0, bfv0, acc[2][0]);
    acc[2][1] = MFMAS(af0, bfv1, acc[2][1]);
    acc[3][0] = MFMAS(af1, bfv0, acc[3][0]);
    acc[3][1] = MFMAS(af1, bfv1, acc[3][1]);
    __builtin_amdgcn_s_setprio(0);

    if ((t & 7) == 7) fold(t >> 3);     // nt-tile boundary (uniform)

    if (stg)            { VMCNT(8); }   // retire tile t+1; t+2,t+3 in flight
    else if (t + 2 < T) { VMCNT(4); }
    else if (t + 1 < T) { VMCNT(0); }
    BARRIER;                            // publish tile t+1
  }

  // writeout
  __syncthreads();
  if (tid < 256) {
    unsigned u = lmin[tid];
    float v = (u & 0x80000000u) ? __uint_as_float(u ^ 0x80000000u) : __uint_as_float(~u);
    minpart[grp * B_SZ + m0 + tid] = fmaxf(esq[m0 + tid] + v, 0.0f);
  }
}

// ---------------- final reductions ----------------

__global__ __launch_bounds__(256) void mse_final_k(const float* __restrict__ part,
                                                   float* __restrict__ msev,
                                                   int nparts, float inv_n) {
  float s = 0.f;
  for (int i = threadIdx.x; i < nparts; i += 256) s += part[i];
#pragma unroll
  for (int off = 1; off < 64; off <<= 1) s += __shfl_xor(s, off);
  __shared__ float sm[4];
  if ((threadIdx.x & 63) == 0) sm[threadIdx.x >> 6] = s;
  __syncthreads();
  if (threadIdx.x == 0) msev[0] = (sm[0] + sm[1] + sm[2] + sm[3]) * inv_n;
}

__global__ void finalize_k(const float* __restrict__ minpart,
                           const float* __restrict__ msev,
                           float* __restrict__ out, int n) {
  int i = blockIdx.x * blockDim.x + threadIdx.x;
  if (i < n) {
    float m = 3.0e38f;
#pragma unroll 8
    for (int gp = 0; gp < NGRP; ++gp) m = fminf(m, minpart[gp * B_SZ + i]);
    out[i] = msev[0] + fminf(50.0f - sqrtf(m), 0.0f) * 5.0f;
  }
}

// ---------------- launch ----------------

extern "C" void kernel_launch(void* const* d_in, const int* in_sizes, int n_in,
                              void* d_out, int out_size, void* d_ws, size_t ws_size,
                              hipStream_t stream) {
  const float* x  = (const float*)d_in[0];
  const float* y  = (const float*)d_in[1];
  const float* W  = (const float*)d_in[2];
  const float* lk = (const float*)d_in[3];
  float* out = (float*)d_out;

  char* ws = (char*)d_ws;
  size_t off = 0;
  auto alloc = [&](size_t bytes) -> void* {
    void* p = ws + off;
    off = (off + bytes + 255) & ~(size_t)255;
    return p;
  };
  unsigned short* xb  = (unsigned short*)alloc((size_t)B_SZ * F_SZ * 2);   // 50.3 MB
  unsigned short* Wt  = (unsigned short*)alloc((size_t)D_SZ * F_SZ * 2);   // 12.6 MB
  unsigned char*  lb  = (unsigned char*)alloc((size_t)N_PAD * D_SZ);       // 51.2 MB fp8
  float* lsq          = (float*)alloc((size_t)N_PAD * 4);
  float* embf         = (float*)alloc((size_t)B_SZ * D_SZ * 4);            // 4 MB
  unsigned char* embq = (unsigned char*)alloc((size_t)B_SZ * D_SZ);        // 1 MB fp8
  float* esq          = (float*)alloc((size_t)B_SZ * 4);
  float* minpart      = (float*)alloc((size_t)NGRP * B_SZ * 4);            // 256 KB
  float* msep         = (float*)alloc(2048 * 4);
  float* msev         = (float*)alloc(256);
  (void)ws_size; (void)in_sizes; (void)n_in; (void)out_size;

  // merged prep
  prep_k<<<PREP_TOTAL, 256, 0, stream>>>(x, y, xb, msep, W, Wt, lk, lb, lsq, embf);

  // emb(f32) = xb @ Wt^T via split-K=12 atomicAdd
  gemm_a_sk<<<768, 256, 0, stream>>>(xb, Wt, embf);
  esq_conv_k<<<B_SZ / 4, 256, 0, stream>>>(embf, embq, esq);

  // persistent fused cdist-min, MX-fp8, 256 blocks (1/CU)
  gemm_min_k<<<256, 512, 0, stream>>>(embq, lb, esq, lsq, minpart);

  mse_final_k<<<1, 256, 0, stream>>>(msep, msev, 2048, 1.0f / ((float)B_SZ * (float)F_SZ));
  finalize_k<<<(B_SZ + 255) / 256, 256, 0, stream>>>(minpart, msev, out, B_SZ);
}

// Round 11
// 333.573 us; speedup vs baseline: 1.4470x; 1.4470x over previous
//
#include <hip/hip_runtime.h>
#include <math.h>

#define B_SZ   2048
#define F_SZ   12288
#define D_SZ   512
#define N_LK   100000
#define N_PAD  100096
#define NT128  782          // N_PAD / 128
#define NGRP   48           // persistent groups (768 blocks = 16 mt x 48 grp, 3/CU)
#define JMAX   17

typedef __attribute__((ext_vector_type(8))) short bf16x8;
typedef __attribute__((ext_vector_type(8))) unsigned short ushort8;
typedef __attribute__((ext_vector_type(4))) float f32x4;
typedef __attribute__((ext_vector_type(16))) float f32x16;
typedef __attribute__((ext_vector_type(8))) int i32x8;

__device__ __forceinline__ unsigned short f2bf(float f) {
  union { float f; unsigned u; } v; v.f = f;
  unsigned r = v.u + 0x7FFFu + ((v.u >> 16) & 1u);
  return (unsigned short)(r >> 16);
}

// f32 -> OCP e4m3fn, round-nearest-even (software, deterministic)
__device__ __forceinline__ unsigned char f2fp8(float f) {
  union { float f; unsigned u; } v; v.f = f;
  unsigned s = (v.u >> 24) & 0x80u;
  unsigned a = v.u & 0x7FFFFFFFu;
  if (a >= 0x43E00000u) return (unsigned char)(s | 0x7E);
  int e32 = (int)(a >> 23) - 127;
  if (e32 < -10) return (unsigned char)s;
  unsigned m24 = (a & 0x7FFFFFu) | 0x800000u;
  int shift = (e32 >= -6) ? 20 : (14 - e32);
  if (shift > 24) return (unsigned char)s;
  unsigned keep = m24 >> shift;
  unsigned rem = m24 & ((1u << shift) - 1u);
  unsigned half = 1u << (shift - 1);
  keep += (rem > half || (rem == half && (keep & 1u))) ? 1u : 0u;
  if (e32 >= -6) {
    if (keep == 16u) { keep = 8u; ++e32; }
    return (unsigned char)(s | ((unsigned)(e32 + 7) << 3) | (keep & 7u));
  }
  if (keep >= 8u) return (unsigned char)(s | 0x08u);
  return (unsigned char)(s | keep);
}

#define GLOAD16(gp, lp) __builtin_amdgcn_global_load_lds( \
    (__attribute__((address_space(1))) void*)(gp),        \
    (__attribute__((address_space(3))) void*)(lp), 16, 0, 0)

#define VMCNT(n) asm volatile("s_waitcnt vmcnt(" #n ")" ::: "memory")
#define BARRIER __builtin_amdgcn_s_barrier()
#define LGKM0 do { asm volatile("s_waitcnt lgkmcnt(0)" ::: "memory"); \
                   __builtin_amdgcn_sched_barrier(0); } while (0)

// scaled MX MFMA: fmt fp8(e4m3); scale bytes all 0x7F = 2^0 = 1.0
#define MFMAS(A, B, C) __builtin_amdgcn_mfma_scale_f32_32x32x64_f8f6f4( \
    (A), (B), (C), 0, 0, 0, 0x7F7F7F7F, 0, 0x7F7F7F7F)

__device__ __forceinline__ i32x8 ldfrag(const char* base, int o0, int o1) {
  int4 lo = *(const int4*)(base + o0);
  int4 hi = *(const int4*)(base + o1);
  i32x8 r = {lo.x, lo.y, lo.z, lo.w, hi.x, hi.y, hi.z, hi.w};
  return r;
}

// packed helpers via inline asm (ROCm 7.2 header gaps: no __hmin2; builtin type mismatch)
__device__ __forceinline__ unsigned cvt_pkrtz_u32(float a, float b) {
  unsigned r;
  asm volatile("v_cvt_pkrtz_f16_f32 %0, %1, %2" : "=v"(r) : "v"(a), "v"(b));
  return r;
}
__device__ __forceinline__ unsigned pk_min_f16(unsigned a, unsigned b) {
  unsigned r;
  asm volatile("v_pk_min_f16 %0, %1, %2" : "=v"(r) : "v"(a), "v"(b));
  return r;
}
__device__ __forceinline__ float f16bits2f(unsigned short us) {
  float r;
  asm volatile("v_cvt_f32_f16 %0, %1" : "=v"(r) : "v"((unsigned)us));
  return r;
}

// ---------------- merged prep ----------------
#define PREP_MSE_BLKS   2048
#define PREP_TW_BLKS    1536
#define PREP_LK_BLKS    (N_PAD / 4)
#define PREP_ZERO_BLKS  512
#define PREP_TOTAL (PREP_MSE_BLKS + PREP_TW_BLKS + PREP_LK_BLKS + PREP_ZERO_BLKS)

__global__ __launch_bounds__(256) void prep_k(
    const float* __restrict__ x, const float* __restrict__ y,
    unsigned short* __restrict__ xb, float* __restrict__ part,
    const float* __restrict__ W, unsigned short* __restrict__ Wt,
    const float* __restrict__ lk, unsigned char* __restrict__ lb,
    float* __restrict__ lsq, float* __restrict__ embf) {
  __shared__ float tl[64][65];
  const int bx = blockIdx.x;
  const int tid = threadIdx.x;

  if (bx < PREP_MSE_BLKS) {
    const long n8 = (long)B_SZ * F_SZ / 8;
    long i = (long)bx * 256 + tid;
    const long stride = (long)PREP_MSE_BLKS * 256;
    float s = 0.f;
    for (; i < n8; i += stride) {
      const float4* px = (const float4*)(x + i * 8);
      const float4* py = (const float4*)(y + i * 8);
      float4 a = px[0], b = px[1];
      float4 c = py[0], d = py[1];
      ushort8 o;
      o[0] = f2bf(a.x); o[1] = f2bf(a.y); o[2] = f2bf(a.z); o[3] = f2bf(a.w);
      o[4] = f2bf(b.x); o[5] = f2bf(b.y); o[6] = f2bf(b.z); o[7] = f2bf(b.w);
      *(ushort8*)(xb + i * 8) = o;
      float t0 = a.x - c.x, t1 = a.y - c.y, t2 = a.z - c.z, t3 = a.w - c.w;
      float t4 = b.x - d.x, t5 = b.y - d.y, t6 = b.z - d.z, t7 = b.w - d.w;
      s += t0 * t0 + t1 * t1 + t2 * t2 + t3 * t3;
      s += t4 * t4 + t5 * t5 + t6 * t6 + t7 * t7;
    }
#pragma unroll
    for (int off = 1; off < 64; off <<= 1) s += __shfl_xor(s, off);
    if ((tid & 63) == 0) tl[0][tid >> 6] = s;
    __syncthreads();
    if (tid == 0) part[bx] = tl[0][0] + tl[0][1] + tl[0][2] + tl[0][3];
  } else if (bx < PREP_MSE_BLKS + PREP_TW_BLKS) {
    const int b = bx - PREP_MSE_BLKS;
    const int r0 = (b % 192) * 64;
    const int c0 = (b / 192) * 64;
#pragma unroll
    for (int p = 0; p < 16; ++p) {
      int idx = p * 256 + tid;
      int r = idx >> 6, c = idx & 63;
      tl[c][r] = W[(size_t)(r0 + r) * D_SZ + c0 + c];
    }
    __syncthreads();
#pragma unroll
    for (int p = 0; p < 2; ++p) {
      int chunk = p * 256 + tid;
      int rr = chunk >> 3, cc = (chunk & 7) * 8;
      ushort8 o;
#pragma unroll
      for (int j = 0; j < 8; ++j) o[j] = f2bf(tl[rr][cc + j]);
      *(ushort8*)&Wt[(size_t)(c0 + rr) * F_SZ + r0 + cc] = o;
    }
  } else if (bx < PREP_MSE_BLKS + PREP_TW_BLKS + PREP_LK_BLKS) {
    // lookup f32 -> fp8 e4m3 (padded) + per-row sumsq (f32); pad sentinel 60000 (f16-safe)
    const int n = (bx - PREP_MSE_BLKS - PREP_TW_BLKS) * 4 + (tid >> 6);
    const int t = tid & 63;
    unsigned lo = 0, hi = 0;
    float s = 0.f;
    if (n < N_LK) {
      const float4* row = (const float4*)(lk + (size_t)n * D_SZ);
      float4 a = row[t * 2], b = row[t * 2 + 1];
      float v[8] = {a.x, a.y, a.z, a.w, b.x, b.y, b.z, b.w};
#pragma unroll
      for (int j = 0; j < 4; ++j) lo |= (unsigned)f2fp8(v[j]) << (8 * j);
#pragma unroll
      for (int j = 0; j < 4; ++j) hi |= (unsigned)f2fp8(v[j + 4]) << (8 * j);
#pragma unroll
      for (int j = 0; j < 8; ++j) s += v[j] * v[j];
    }
    uint2 o2; o2.x = lo; o2.y = hi;
    *(uint2*)&lb[(size_t)n * D_SZ + t * 8] = o2;
#pragma unroll
    for (int off = 1; off < 64; off <<= 1) s += __shfl_xor(s, off);
    if (t == 0) lsq[n] = (n < N_LK) ? s : 60000.0f;
  } else {
    long i = (long)(bx - PREP_MSE_BLKS - PREP_TW_BLKS - PREP_LK_BLKS) * 256 + tid;
    const long n4 = (long)B_SZ * D_SZ / 4;
    const long stride = (long)PREP_ZERO_BLKS * 256;
    float4 z = {0.f, 0.f, 0.f, 0.f};
    for (; i < n4; i += stride) ((float4*)embf)[i] = z;
  }
}

// ---------------- GEMM-A split-K=12 (bf16, unchanged) ----------------
__global__ __launch_bounds__(256) void gemm_a_sk(const unsigned short* __restrict__ A,
                                                 const unsigned short* __restrict__ Bm,
                                                 float* __restrict__ embf) {
  __shared__ unsigned short lsA[128 * 32];
  __shared__ unsigned short lsB[128 * 32];
  const int tid = threadIdx.x;
  const int bid = blockIdx.x;
  const int mt = bid & 15, dt = (bid >> 4) & 3, ks = bid >> 6;
  const int m0 = mt * 128, n0 = dt * 128;
  const int k0base = ks * 1024;
  const int l = tid & 63;
  const int w = tid >> 6;
  const int wr = (w >> 1) * 64, wc = (w & 1) * 64;
  const int g = l >> 4, lane16 = l & 15;

  const int srow = tid >> 2;
  const int scol = (tid & 3) * 8;
  const unsigned short* Ag0 = A + (size_t)(m0 + srow) * F_SZ + scol + k0base;
  const unsigned short* Ag1 = A + (size_t)(m0 + 64 + srow) * F_SZ + scol + k0base;
  const unsigned short* Bg0 = Bm + (size_t)(n0 + srow) * F_SZ + scol + k0base;
  const unsigned short* Bg1 = Bm + (size_t)(n0 + 64 + srow) * F_SZ + scol + k0base;
  unsigned short* la0 = &lsA[tid * 8];
  unsigned short* la1 = &lsA[2048 + tid * 8];
  unsigned short* lb0 = &lsB[tid * 8];
  unsigned short* lb1 = &lsB[2048 + tid * 8];

  int ar[4], br[4];
#pragma unroll
  for (int m = 0; m < 4; ++m) ar[m] = (wr + m * 16 + lane16) * 32 + g * 8;
#pragma unroll
  for (int n = 0; n < 4; ++n) br[n] = (wc + n * 16 + lane16) * 32 + g * 8;

  f32x4 acc[4][4] = {};

  for (int k0 = 0; k0 < 1024; k0 += 32) {
    GLOAD16(Ag0 + k0, la0);
    GLOAD16(Ag1 + k0, la1);
    GLOAD16(Bg0 + k0, lb0);
    GLOAD16(Bg1 + k0, lb1);
    __syncthreads();
    bf16x8 af[4], bfv[4];
#pragma unroll
    for (int m = 0; m < 4; ++m) af[m] = *(const bf16x8*)&lsA[ar[m]];
#pragma unroll
    for (int n = 0; n < 4; ++n) bfv[n] = *(const bf16x8*)&lsB[br[n]];
#pragma unroll
    for (int m = 0; m < 4; ++m)
#pragma unroll
      for (int n = 0; n < 4; ++n)
        acc[m][n] = __builtin_amdgcn_mfma_f32_16x16x32_bf16(af[m], bfv[n], acc[m][n], 0, 0, 0);
    __syncthreads();
  }
#pragma unroll
  for (int m = 0; m < 4; ++m)
#pragma unroll
    for (int n = 0; n < 4; ++n)
#pragma unroll
      for (int r = 0; r < 4; ++r) {
        int row = m0 + wr + m * 16 + g * 4 + r;
        int col = n0 + wc + n * 16 + lane16;
        atomicAdd(&embf[(size_t)row * D_SZ + col], acc[m][n][r]);
      }
}

// embf f32 -> embq fp8 + per-row esq (f32)
__global__ __launch_bounds__(256) void esq_conv_k(const float* __restrict__ embf,
                                                  unsigned char* __restrict__ embq,
                                                  float* __restrict__ esq) {
  int r = blockIdx.x * 4 + (threadIdx.x >> 6);
  int t = threadIdx.x & 63;
  const float4* row = (const float4*)(embf + (size_t)r * D_SZ);
  float4 a = row[t * 2], b = row[t * 2 + 1];
  float v[8] = {a.x, a.y, a.z, a.w, b.x, b.y, b.z, b.w};
  unsigned lo = 0, hi = 0;
  float s = 0.f;
#pragma unroll
  for (int j = 0; j < 4; ++j) lo |= (unsigned)f2fp8(v[j]) << (8 * j);
#pragma unroll
  for (int j = 0; j < 4; ++j) hi |= (unsigned)f2fp8(v[j + 4]) << (8 * j);
#pragma unroll
  for (int j = 0; j < 8; ++j) s += v[j] * v[j];
  uint2 o2; o2.x = lo; o2.y = hi;
  *(uint2*)&embq[(size_t)r * D_SZ + t * 8] = o2;
#pragma unroll
  for (int off = 1; off < 64; off <<= 1) s += __shfl_xor(s, off);
  if (t == 0) esq[r] = s;
}

// ---------------- GEMM-B: persistent fused cdist-min, fp8 32x32x64, 128x128, 3/CU ------
// R5's proven skeleton (128x128, 4 waves 2x2, 2-ring LDS, counted VMCNT(4), 3 blocks/CU,
// XCD-aligned B-sharing) with fp8 MFMA: BK=64, wave tile 64x64 = 2x2 32x32 frags,
// acc = f32x16[2][2] (AGPR). Fold = pure-register per-lane running min packed f16
// (v_cvt_pkrtz + v_pk_min_f16; no shfl, no atomics); cross-lane reduce once at writeout.
// lsq preloaded to LDS so the main loop issues ONLY staging vmem -> counted vmcnt exact.
__global__ __launch_bounds__(256, 3) void gemm_min_k(
    const unsigned char* __restrict__ Aq,   // embq [2048][512] fp8
    const unsigned char* __restrict__ Bq,   // lb   [100096][512] fp8
    const float* __restrict__ esq, const float* __restrict__ lsq,
    float* __restrict__ minpart) {          // [NGRP][2048]
  __shared__ char lsA[2 * 8192];
  __shared__ char lsB[2 * 8192];
  __shared__ float lsq_lds[JMAX * 128];

  const int tid = threadIdx.x;
  const int grp = blockIdx.x % NGRP;
  const int mt = blockIdx.x / NGRP;     // 0..15
  const int m0 = mt * 128;
  const int J = (NT128 - grp + NGRP - 1) / NGRP;  // 16 or 17
  const int T = J * 8;                            // K-64 steps

  const int l = tid & 63;
  const int wid = tid >> 6;
  const int wm = wid >> 1, wn = wid & 1;          // 2x2 waves, tile 64x64
  const int hi = l >> 5, l31 = l & 31;

  // staging: linear LDS dest; source 16B slot pre-swizzled (slot' = slot^((row>>1)&3))
  const int srow = tid >> 2;                      // 0..63 (per half)
  const int sslot = (tid & 3) ^ ((tid >> 3) & 3);
  const unsigned char* Abase = Aq + (size_t)(m0 + srow) * D_SZ + sslot * 16;
  const unsigned char* Bbase = Bq + (size_t)srow * D_SZ + sslot * 16;

  // fragment ds_read byte offsets (2x b128 per 32B frag, swizzled slots)
  int aro[2][2], bro[2][2];
#pragma unroll
  for (int mf = 0; mf < 2; ++mf) {
    int row = wm * 64 + mf * 32 + l31;
#pragma unroll
    for (int j = 0; j < 2; ++j)
      aro[mf][j] = row * 64 + (((hi * 2 + j) ^ ((l31 >> 1) & 3)) << 4);
  }
#pragma unroll
  for (int nf = 0; nf < 2; ++nf) {
    int row = wn * 64 + nf * 32 + l31;
#pragma unroll
    for (int j = 0; j < 2; ++j)
      bro[nf][j] = row * 64 + (((hi * 2 + j) ^ ((l31 >> 1) & 3)) << 4);
  }

  f32x16 acc[2][2] = {};
  const f32x16 fzero = {};
  unsigned rmin2[2][8];
#pragma unroll
  for (int mf = 0; mf < 2; ++mf)
#pragma unroll
    for (int q = 0; q < 8; ++q) rmin2[mf][q] = 0x7BFF7BFFu;  // +65504 packed f16 x2

  // preload lsq tile columns to LDS (loop issues no other vmem afterwards)
  for (int j = 0; j < J; ++j)
    if (tid < 128) lsq_lds[j * 128 + tid] = lsq[(grp + NGRP * j) * 128 + tid];
  __syncthreads();   // drains vmcnt+lgkm -> clean baseline for counted waits

  auto stage = [&](int s) {
    const int b = s & 1;
    const int koff = (s & 7) * 64;
    const size_t boff = (size_t)(grp + NGRP * (s >> 3)) * 128 * D_SZ;
    GLOAD16(Abase + koff, lsA + b * 8192 + tid * 16);
    GLOAD16(Abase + (size_t)64 * D_SZ + koff, lsA + b * 8192 + 4096 + tid * 16);
    GLOAD16(Bbase + boff + koff, lsB + b * 8192 + tid * 16);
    GLOAD16(Bbase + boff + (size_t)64 * D_SZ + koff, lsB + b * 8192 + 4096 + tid * 16);
  };
  auto fold = [&](int j) {
    const float lq0 = lsq_lds[j * 128 + wn * 64 + l31];
    const float lq1 = lsq_lds[j * 128 + wn * 64 + 32 + l31];
#pragma unroll
    for (int mf = 0; mf < 2; ++mf) {
#pragma unroll
      for (int q = 0; q < 8; ++q) {
        float v0 = fminf(fmaf(-2.f, acc[mf][0][2 * q], lq0),
                         fmaf(-2.f, acc[mf][1][2 * q], lq1));
        float v1 = fminf(fmaf(-2.f, acc[mf][0][2 * q + 1], lq0),
                         fmaf(-2.f, acc[mf][1][2 * q + 1], lq1));
        rmin2[mf][q] = pk_min_f16(rmin2[mf][q], cvt_pkrtz_u32(v0, v1));
      }
      acc[mf][0] = fzero;
      acc[mf][1] = fzero;
    }
  };

  // prologue: tiles 0,1 in flight; retire tile 0
  stage(0); stage(1);
  VMCNT(4);
  BARRIER;

  for (int t = 0; t < T; ++t) {
    const int b = t & 1;
    const char* pA = lsA + b * 8192;
    const char* pB = lsB + b * 8192;
    i32x8 bfv0 = ldfrag(pB, bro[0][0], bro[0][1]);
    i32x8 bfv1 = ldfrag(pB, bro[1][0], bro[1][1]);
    i32x8 af0 = ldfrag(pA, aro[0][0], aro[0][1]);
    i32x8 af1 = ldfrag(pA, aro[1][0], aro[1][1]);
    LGKM0;
    BARRIER;                         // all waves' reads done -> buf b reusable
    if (t + 2 < T) stage(t + 2);     // uniform branch
    __builtin_amdgcn_s_setprio(1);
    acc[0][0] = MFMAS(af0, bfv0, acc[0][0]);
    acc[0][1] = MFMAS(af0, bfv1, acc[0][1]);
    acc[1][0] = MFMAS(af1, bfv0, acc[1][0]);
    acc[1][1] = MFMAS(af1, bfv1, acc[1][1]);
    __builtin_amdgcn_s_setprio(0);
    if ((t & 7) == 7) fold(t >> 3);  // nt-tile boundary (uniform)
    if (t + 2 < T) { VMCNT(4); }     // retire tile t+1; t+2 in flight
    else if (t + 1 < T) { VMCNT(0); }
    BARRIER;                         // publish tile t+1
  }

  // writeout: cross-lane min over the 32 cols, 2 lanes (hi) cover distinct row halves
#pragma unroll
  for (int mf = 0; mf < 2; ++mf)
#pragma unroll
    for (int r = 0; r < 16; ++r) {
      unsigned u = rmin2[mf][r >> 1];
      unsigned short us = (r & 1) ? (unsigned short)(u >> 16) : (unsigned short)(u & 0xFFFFu);
      float v = f16bits2f(us);
#pragma unroll
      for (int off = 1; off < 32; off <<= 1) v = fminf(v, __shfl_xor(v, off));
      if (l31 == 0) {
        int row = m0 + wm * 64 + mf * 32 + (r & 3) + 8 * (r >> 2) + 4 * hi;
        minpart[grp * B_SZ + row] = fmaxf(esq[row] + v, 0.0f);
      }
    }
}

// ---------------- final reductions ----------------

__global__ __launch_bounds__(256) void mse_final_k(const float* __restrict__ part,
                                                   float* __restrict__ msev,
                                                   int nparts, float inv_n) {
  float s = 0.f;
  for (int i = threadIdx.x; i < nparts; i += 256) s += part[i];
#pragma unroll
  for (int off = 1; off < 64; off <<= 1) s += __shfl_xor(s, off);
  __shared__ float sm[4];
  if ((threadIdx.x & 63) == 0) sm[threadIdx.x >> 6] = s;
  __syncthreads();
  if (threadIdx.x == 0) msev[0] = (sm[0] + sm[1] + sm[2] + sm[3]) * inv_n;
}

__global__ void finalize_k(const float* __restrict__ minpart,
                           const float* __restrict__ msev,
                           float* __restrict__ out, int n) {
  int i = blockIdx.x * blockDim.x + threadIdx.x;
  if (i < n) {
    float m = 3.0e38f;
#pragma unroll 8
    for (int gp = 0; gp < NGRP; ++gp) m = fminf(m, minpart[gp * B_SZ + i]);
    out[i] = msev[0] + fminf(50.0f - sqrtf(m), 0.0f) * 5.0f;
  }
}

// ---------------- launch ----------------

extern "C" void kernel_launch(void* const* d_in, const int* in_sizes, int n_in,
                              void* d_out, int out_size, void* d_ws, size_t ws_size,
                              hipStream_t stream) {
  const float* x  = (const float*)d_in[0];
  const float* y  = (const float*)d_in[1];
  const float* W  = (const float*)d_in[2];
  const float* lk = (const float*)d_in[3];
  float* out = (float*)d_out;

  char* ws = (char*)d_ws;
  size_t off = 0;
  auto alloc = [&](size_t bytes) -> void* {
    void* p = ws + off;
    off = (off + bytes + 255) & ~(size_t)255;
    return p;
  };
  unsigned short* xb  = (unsigned short*)alloc((size_t)B_SZ * F_SZ * 2);   // 50.3 MB
  unsigned short* Wt  = (unsigned short*)alloc((size_t)D_SZ * F_SZ * 2);   // 12.6 MB
  unsigned char*  lb  = (unsigned char*)alloc((size_t)N_PAD * D_SZ);       // 51.2 MB fp8
  float* lsq          = (float*)alloc((size_t)N_PAD * 4);
  float* embf         = (float*)alloc((size_t)B_SZ * D_SZ * 4);            // 4 MB
  unsigned char* embq = (unsigned char*)alloc((size_t)B_SZ * D_SZ);        // 1 MB fp8
  float* esq          = (float*)alloc((size_t)B_SZ * 4);
  float* minpart      = (float*)alloc((size_t)NGRP * B_SZ * 4);            // 384 KB
  float* msep         = (float*)alloc(2048 * 4);
  float* msev         = (float*)alloc(256);
  (void)ws_size; (void)in_sizes; (void)n_in; (void)out_size;

  // merged prep
  prep_k<<<PREP_TOTAL, 256, 0, stream>>>(x, y, xb, msep, W, Wt, lk, lb, lsq, embf);

  // emb(f32) = xb @ Wt^T via split-K=12 atomicAdd
  gemm_a_sk<<<768, 256, 0, stream>>>(xb, Wt, embf);
  esq_conv_k<<<B_SZ / 4, 256, 0, stream>>>(embf, embq, esq);

  // persistent fused cdist-min, fp8, 768 blocks (3/CU)
  gemm_min_k<<<768, 256, 0, stream>>>(embq, lb, esq, lsq, minpart);

  mse_final_k<<<1, 256, 0, stream>>>(msep, msev, 2048, 1.0f / ((float)B_SZ * (float)F_SZ));
  finalize_k<<<(B_SZ + 255) / 256, 256, 0, stream>>>(minpart, msev, out, B_SZ);
}

// Round 12
// 290.414 us; speedup vs baseline: 1.6620x; 1.1486x over previous
//
#include <hip/hip_runtime.h>
#include <math.h>

#define B_SZ   2048
#define F_SZ   12288
#define D_SZ   512
#define N_LK   100000
#define N_PAD  100096
#define NT128  782          // N_PAD / 128
#define NGRP   48           // persistent groups (768 blocks = 16 mt x 48 grp, 3/CU)
#define JMAX   17

typedef __attribute__((ext_vector_type(8))) short bf16x8;
typedef __attribute__((ext_vector_type(8))) unsigned short ushort8;
typedef __attribute__((ext_vector_type(4))) float f32x4;
typedef __attribute__((ext_vector_type(16))) float f32x16;
typedef __attribute__((ext_vector_type(8))) int i32x8;

// f32 -> OCP e4m3fn, round-nearest-even (software fallback)
__device__ __forceinline__ unsigned char f2fp8_sw(float f) {
  union { float f; unsigned u; } v; v.f = f;
  unsigned s = (v.u >> 24) & 0x80u;
  unsigned a = v.u & 0x7FFFFFFFu;
  if (a >= 0x43E00000u) return (unsigned char)(s | 0x7E);
  int e32 = (int)(a >> 23) - 127;
  if (e32 < -10) return (unsigned char)s;
  unsigned m24 = (a & 0x7FFFFFu) | 0x800000u;
  int shift = (e32 >= -6) ? 20 : (14 - e32);
  if (shift > 24) return (unsigned char)s;
  unsigned keep = m24 >> shift;
  unsigned rem = m24 & ((1u << shift) - 1u);
  unsigned half = 1u << (shift - 1);
  keep += (rem > half || (rem == half && (keep & 1u))) ? 1u : 0u;
  if (e32 >= -6) {
    if (keep == 16u) { keep = 8u; ++e32; }
    return (unsigned char)(s | ((unsigned)(e32 + 7) << 3) | (keep & 7u));
  }
  if (keep >= 8u) return (unsigned char)(s | 0x08u);
  return (unsigned char)(s | keep);
}

// pack 8 f32 -> 8 fp8 bytes (hardware v_cvt_pk_fp8_f32 when available)
__device__ __forceinline__ uint2 fp8pack8(const float* v) {
#if __has_builtin(__builtin_amdgcn_cvt_pk_fp8_f32)
  int lo = 0, hi = 0;
  lo = __builtin_amdgcn_cvt_pk_fp8_f32(v[0], v[1], lo, false);
  lo = __builtin_amdgcn_cvt_pk_fp8_f32(v[2], v[3], lo, true);
  hi = __builtin_amdgcn_cvt_pk_fp8_f32(v[4], v[5], hi, false);
  hi = __builtin_amdgcn_cvt_pk_fp8_f32(v[6], v[7], hi, true);
  uint2 r; r.x = (unsigned)lo; r.y = (unsigned)hi;
  return r;
#else
  unsigned lo = 0, hi = 0;
#pragma unroll
  for (int j = 0; j < 4; ++j) lo |= (unsigned)f2fp8_sw(v[j]) << (8 * j);
#pragma unroll
  for (int j = 0; j < 4; ++j) hi |= (unsigned)f2fp8_sw(v[j + 4]) << (8 * j);
  uint2 r; r.x = lo; r.y = hi;
  return r;
#endif
}

#define GLOAD16(gp, lp) __builtin_amdgcn_global_load_lds( \
    (__attribute__((address_space(1))) void*)(gp),        \
    (__attribute__((address_space(3))) void*)(lp), 16, 0, 0)

#define VMCNT(n) asm volatile("s_waitcnt vmcnt(" #n ")" ::: "memory")
#define BARRIER __builtin_amdgcn_s_barrier()
#define LGKM0 do { asm volatile("s_waitcnt lgkmcnt(0)" ::: "memory"); \
                   __builtin_amdgcn_sched_barrier(0); } while (0)

// scaled MX MFMA: fmt fp8(e4m3); scale bytes replicated (op_sel-independent)
#define MFMAS(A, B, C) __builtin_amdgcn_mfma_scale_f32_32x32x64_f8f6f4( \
    (A), (B), (C), 0, 0, 0, 0x7F7F7F7F, 0, 0x7F7F7F7F)
// B carries W*64 -> scale_b = 2^-6 (byte 0x79 = 121 -> 2^(121-127))
#define MFMAS_W(A, B, C) __builtin_amdgcn_mfma_scale_f32_32x32x64_f8f6f4( \
    (A), (B), (C), 0, 0, 0, 0x7F7F7F7F, 0, 0x79797979)

__device__ __forceinline__ i32x8 ldfrag(const char* base, int o0, int o1) {
  int4 lo = *(const int4*)(base + o0);
  int4 hi = *(const int4*)(base + o1);
  i32x8 r = {lo.x, lo.y, lo.z, lo.w, hi.x, hi.y, hi.z, hi.w};
  return r;
}

// packed f16 helpers via inline asm (ROCm 7.2 header gaps)
__device__ __forceinline__ unsigned cvt_pkrtz_u32(float a, float b) {
  unsigned r;
  asm volatile("v_cvt_pkrtz_f16_f32 %0, %1, %2" : "=v"(r) : "v"(a), "v"(b));
  return r;
}
__device__ __forceinline__ unsigned pk_min_f16(unsigned a, unsigned b) {
  unsigned r;
  asm volatile("v_pk_min_f16 %0, %1, %2" : "=v"(r) : "v"(a), "v"(b));
  return r;
}
__device__ __forceinline__ float f16bits2f(unsigned short us) {
  float r;
  asm volatile("v_cvt_f32_f16 %0, %1" : "=v"(r) : "v"((unsigned)us));
  return r;
}

// ---------------- merged prep ----------------
#define PREP_MSE_BLKS   2048
#define PREP_TW_BLKS    1536
#define PREP_LK_BLKS    (N_PAD / 4)
#define PREP_ZERO_BLKS  512
#define PREP_TOTAL (PREP_MSE_BLKS + PREP_TW_BLKS + PREP_LK_BLKS + PREP_ZERO_BLKS)

__global__ __launch_bounds__(256) void prep_k(
    const float* __restrict__ x, const float* __restrict__ y,
    unsigned char* __restrict__ xa8, float* __restrict__ part,
    const float* __restrict__ W, unsigned char* __restrict__ Wt8,
    const float* __restrict__ lk, unsigned char* __restrict__ lb,
    float* __restrict__ lsq, float* __restrict__ embf) {
  __shared__ float tl[64][65];
  const int bx = blockIdx.x;
  const int tid = threadIdx.x;

  if (bx < PREP_MSE_BLKS) {
    // ---- x->fp8 + mse partial ----
    const long n8 = (long)B_SZ * F_SZ / 8;
    long i = (long)bx * 256 + tid;
    const long stride = (long)PREP_MSE_BLKS * 256;
    float s = 0.f;
    for (; i < n8; i += stride) {
      const float4* px = (const float4*)(x + i * 8);
      const float4* py = (const float4*)(y + i * 8);
      float4 a = px[0], b = px[1];
      float4 c = py[0], d = py[1];
      float v[8] = {a.x, a.y, a.z, a.w, b.x, b.y, b.z, b.w};
      *(uint2*)(xa8 + i * 8) = fp8pack8(v);
      float t0 = a.x - c.x, t1 = a.y - c.y, t2 = a.z - c.z, t3 = a.w - c.w;
      float t4 = b.x - d.x, t5 = b.y - d.y, t6 = b.z - d.z, t7 = b.w - d.w;
      s += t0 * t0 + t1 * t1 + t2 * t2 + t3 * t3;
      s += t4 * t4 + t5 * t5 + t6 * t6 + t7 * t7;
    }
#pragma unroll
    for (int off = 1; off < 64; off <<= 1) s += __shfl_xor(s, off);
    if ((tid & 63) == 0) tl[0][tid >> 6] = s;
    __syncthreads();
    if (tid == 0) part[bx] = tl[0][0] + tl[0][1] + tl[0][2] + tl[0][3];
  } else if (bx < PREP_MSE_BLKS + PREP_TW_BLKS) {
    // ---- W [F,D] f32 -> Wt8 [D,F] fp8 scaled x64 (e4m3 normal range) ----
    const int b = bx - PREP_MSE_BLKS;
    const int r0 = (b % 192) * 64;  // F dim
    const int c0 = (b / 192) * 64;  // D dim
#pragma unroll
    for (int p = 0; p < 16; ++p) {
      int idx = p * 256 + tid;
      int r = idx >> 6, c = idx & 63;
      tl[c][r] = W[(size_t)(r0 + r) * D_SZ + c0 + c];
    }
    __syncthreads();
#pragma unroll
    for (int p = 0; p < 2; ++p) {
      int chunk = p * 256 + tid;
      int rr = chunk >> 3, cc = (chunk & 7) * 8;
      float v[8];
#pragma unroll
      for (int j = 0; j < 8; ++j) v[j] = tl[rr][cc + j] * 64.0f;
      *(uint2*)&Wt8[(size_t)(c0 + rr) * F_SZ + r0 + cc] = fp8pack8(v);
    }
  } else if (bx < PREP_MSE_BLKS + PREP_TW_BLKS + PREP_LK_BLKS) {
    // ---- lookup f32 -> fp8 (padded) + per-row sumsq (f32); pad sentinel 60000 ----
    const int n = (bx - PREP_MSE_BLKS - PREP_TW_BLKS) * 4 + (tid >> 6);
    const int t = tid & 63;
    uint2 o2 = {0u, 0u};
    float s = 0.f;
    if (n < N_LK) {
      const float4* row = (const float4*)(lk + (size_t)n * D_SZ);
      float4 a = row[t * 2], b = row[t * 2 + 1];
      float v[8] = {a.x, a.y, a.z, a.w, b.x, b.y, b.z, b.w};
      o2 = fp8pack8(v);
#pragma unroll
      for (int j = 0; j < 8; ++j) s += v[j] * v[j];
    }
    *(uint2*)&lb[(size_t)n * D_SZ + t * 8] = o2;
#pragma unroll
    for (int off = 1; off < 64; off <<= 1) s += __shfl_xor(s, off);
    if (t == 0) lsq[n] = (n < N_LK) ? s : 60000.0f;
  } else {
    long i = (long)(bx - PREP_MSE_BLKS - PREP_TW_BLKS - PREP_LK_BLKS) * 256 + tid;
    const long n4 = (long)B_SZ * D_SZ / 4;
    const long stride = (long)PREP_ZERO_BLKS * 256;
    float4 z = {0.f, 0.f, 0.f, 0.f};
    for (; i < n4; i += stride) ((float4*)embf)[i] = z;
  }
}

// ---------------- GEMM-A fp8 split-K=12: embf += xa8 @ Wt8^T (x 2^-6 on B) ----------
// grid 768 = mt(16) x dt(4) x ks(12); K-slice 1024 = 16 K-64 steps; 3 blocks/CU.
// Clones gemm_min's verified staging/swizzle/fragment structure; atomicAdd f32
// epilogue (12 writers/address; hinge-clamped output tolerant to order).
__global__ __launch_bounds__(256, 3) void gemm_a_f8(
    const unsigned char* __restrict__ Aq,   // xa8 [2048][12288] fp8
    const unsigned char* __restrict__ Bq,   // Wt8 [512][12288] fp8 (x64)
    float* __restrict__ embf) {
  __shared__ char lsA[2 * 8192];
  __shared__ char lsB[2 * 8192];
  const int tid = threadIdx.x;
  const int bid = blockIdx.x;
  const int mt = bid & 15, dt = (bid >> 4) & 3, ks = bid >> 6;
  const int m0 = mt * 128, n0 = dt * 128;
  const size_t kbase = (size_t)ks * 1024;

  const int l = tid & 63;
  const int wid = tid >> 6;
  const int wm = wid >> 1, wn = wid & 1;
  const int hi = l >> 5, l31 = l & 31;

  const int srow = tid >> 2;
  const int sslot = (tid & 3) ^ ((tid >> 3) & 3);
  const unsigned char* Abase = Aq + (size_t)(m0 + srow) * F_SZ + kbase + sslot * 16;
  const unsigned char* Bbase = Bq + (size_t)(n0 + srow) * F_SZ + kbase + sslot * 16;

  int aro[2][2], bro[2][2];
#pragma unroll
  for (int mf = 0; mf < 2; ++mf) {
    int row = wm * 64 + mf * 32 + l31;
#pragma unroll
    for (int j = 0; j < 2; ++j)
      aro[mf][j] = row * 64 + (((hi * 2 + j) ^ ((l31 >> 1) & 3)) << 4);
  }
#pragma unroll
  for (int nf = 0; nf < 2; ++nf) {
    int row = wn * 64 + nf * 32 + l31;
#pragma unroll
    for (int j = 0; j < 2; ++j)
      bro[nf][j] = row * 64 + (((hi * 2 + j) ^ ((l31 >> 1) & 3)) << 4);
  }

  f32x16 acc[2][2] = {};

  auto stage = [&](int s) {
    const int b = s & 1;
    const int koff = s * 64;
    GLOAD16(Abase + koff, lsA + b * 8192 + tid * 16);
    GLOAD16(Abase + (size_t)64 * F_SZ + koff, lsA + b * 8192 + 4096 + tid * 16);
    GLOAD16(Bbase + koff, lsB + b * 8192 + tid * 16);
    GLOAD16(Bbase + (size_t)64 * F_SZ + koff, lsB + b * 8192 + 4096 + tid * 16);
  };

  stage(0); stage(1);
  VMCNT(4);
  BARRIER;

  for (int t = 0; t < 16; ++t) {
    const int b = t & 1;
    const char* pA = lsA + b * 8192;
    const char* pB = lsB + b * 8192;
    i32x8 bfv0 = ldfrag(pB, bro[0][0], bro[0][1]);
    i32x8 bfv1 = ldfrag(pB, bro[1][0], bro[1][1]);
    i32x8 af0 = ldfrag(pA, aro[0][0], aro[0][1]);
    i32x8 af1 = ldfrag(pA, aro[1][0], aro[1][1]);
    LGKM0;
    BARRIER;
    if (t + 2 < 16) stage(t + 2);
    __builtin_amdgcn_s_setprio(1);
    acc[0][0] = MFMAS_W(af0, bfv0, acc[0][0]);
    acc[0][1] = MFMAS_W(af0, bfv1, acc[0][1]);
    acc[1][0] = MFMAS_W(af1, bfv0, acc[1][0]);
    acc[1][1] = MFMAS_W(af1, bfv1, acc[1][1]);
    __builtin_amdgcn_s_setprio(0);
    if (t + 2 < 16) { VMCNT(4); }
    else if (t + 1 < 16) { VMCNT(0); }
    BARRIER;
  }

  // epilogue: C/D 32x32 layout row=(r&3)+8*(r>>2)+4*hi, col=l31
#pragma unroll
  for (int mf = 0; mf < 2; ++mf)
#pragma unroll
    for (int nf = 0; nf < 2; ++nf)
#pragma unroll
      for (int r = 0; r < 16; ++r) {
        int row = m0 + wm * 64 + mf * 32 + (r & 3) + 8 * (r >> 2) + 4 * hi;
        int col = n0 + wn * 64 + nf * 32 + l31;
        atomicAdd(&embf[(size_t)row * D_SZ + col], acc[mf][nf][r]);
      }
}

// embf f32 -> embq fp8 + per-row esq (f32)
__global__ __launch_bounds__(256) void esq_conv_k(const float* __restrict__ embf,
                                                  unsigned char* __restrict__ embq,
                                                  float* __restrict__ esq) {
  int r = blockIdx.x * 4 + (threadIdx.x >> 6);
  int t = threadIdx.x & 63;
  const float4* row = (const float4*)(embf + (size_t)r * D_SZ);
  float4 a = row[t * 2], b = row[t * 2 + 1];
  float v[8] = {a.x, a.y, a.z, a.w, b.x, b.y, b.z, b.w};
  float s = 0.f;
#pragma unroll
  for (int j = 0; j < 8; ++j) s += v[j] * v[j];
  *(uint2*)&embq[(size_t)r * D_SZ + t * 8] = fp8pack8(v);
#pragma unroll
  for (int off = 1; off < 64; off <<= 1) s += __shfl_xor(s, off);
  if (t == 0) esq[r] = s;
}

// ---------------- GEMM-B: persistent fused cdist-min, fp8 32x32x64 (R11, verified) ----
__global__ __launch_bounds__(256, 3) void gemm_min_k(
    const unsigned char* __restrict__ Aq,   // embq [2048][512] fp8
    const unsigned char* __restrict__ Bq,   // lb   [100096][512] fp8
    const float* __restrict__ esq, const float* __restrict__ lsq,
    float* __restrict__ minpart) {          // [NGRP][2048]
  __shared__ char lsA[2 * 8192];
  __shared__ char lsB[2 * 8192];
  __shared__ float lsq_lds[JMAX * 128];

  const int tid = threadIdx.x;
  const int grp = blockIdx.x % NGRP;
  const int mt = blockIdx.x / NGRP;     // 0..15
  const int m0 = mt * 128;
  const int J = (NT128 - grp + NGRP - 1) / NGRP;  // 16 or 17
  const int T = J * 8;                            // K-64 steps

  const int l = tid & 63;
  const int wid = tid >> 6;
  const int wm = wid >> 1, wn = wid & 1;          // 2x2 waves, tile 64x64
  const int hi = l >> 5, l31 = l & 31;

  const int srow = tid >> 2;
  const int sslot = (tid & 3) ^ ((tid >> 3) & 3);
  const unsigned char* Abase = Aq + (size_t)(m0 + srow) * D_SZ + sslot * 16;
  const unsigned char* Bbase = Bq + (size_t)srow * D_SZ + sslot * 16;

  int aro[2][2], bro[2][2];
#pragma unroll
  for (int mf = 0; mf < 2; ++mf) {
    int row = wm * 64 + mf * 32 + l31;
#pragma unroll
    for (int j = 0; j < 2; ++j)
      aro[mf][j] = row * 64 + (((hi * 2 + j) ^ ((l31 >> 1) & 3)) << 4);
  }
#pragma unroll
  for (int nf = 0; nf < 2; ++nf) {
    int row = wn * 64 + nf * 32 + l31;
#pragma unroll
    for (int j = 0; j < 2; ++j)
      bro[nf][j] = row * 64 + (((hi * 2 + j) ^ ((l31 >> 1) & 3)) << 4);
  }

  f32x16 acc[2][2] = {};
  const f32x16 fzero = {};
  unsigned rmin2[2][8];
#pragma unroll
  for (int mf = 0; mf < 2; ++mf)
#pragma unroll
    for (int q = 0; q < 8; ++q) rmin2[mf][q] = 0x7BFF7BFFu;  // +65504 packed f16 x2

  for (int j = 0; j < J; ++j)
    if (tid < 128) lsq_lds[j * 128 + tid] = lsq[(grp + NGRP * j) * 128 + tid];
  __syncthreads();   // drains vmcnt+lgkm -> clean baseline for counted waits

  auto stage = [&](int s) {
    const int b = s & 1;
    const int koff = (s & 7) * 64;
    const size_t boff = (size_t)(grp + NGRP * (s >> 3)) * 128 * D_SZ;
    GLOAD16(Abase + koff, lsA + b * 8192 + tid * 16);
    GLOAD16(Abase + (size_t)64 * D_SZ + koff, lsA + b * 8192 + 4096 + tid * 16);
    GLOAD16(Bbase + boff + koff, lsB + b * 8192 + tid * 16);
    GLOAD16(Bbase + boff + (size_t)64 * D_SZ + koff, lsB + b * 8192 + 4096 + tid * 16);
  };
  auto fold = [&](int j) {
    const float lq0 = lsq_lds[j * 128 + wn * 64 + l31];
    const float lq1 = lsq_lds[j * 128 + wn * 64 + 32 + l31];
#pragma unroll
    for (int mf = 0; mf < 2; ++mf) {
#pragma unroll
      for (int q = 0; q < 8; ++q) {
        float v0 = fminf(fmaf(-2.f, acc[mf][0][2 * q], lq0),
                         fmaf(-2.f, acc[mf][1][2 * q], lq1));
        float v1 = fminf(fmaf(-2.f, acc[mf][0][2 * q + 1], lq0),
                         fmaf(-2.f, acc[mf][1][2 * q + 1], lq1));
        rmin2[mf][q] = pk_min_f16(rmin2[mf][q], cvt_pkrtz_u32(v0, v1));
      }
      acc[mf][0] = fzero;
      acc[mf][1] = fzero;
    }
  };

  stage(0); stage(1);
  VMCNT(4);
  BARRIER;

  for (int t = 0; t < T; ++t) {
    const int b = t & 1;
    const char* pA = lsA + b * 8192;
    const char* pB = lsB + b * 8192;
    i32x8 bfv0 = ldfrag(pB, bro[0][0], bro[0][1]);
    i32x8 bfv1 = ldfrag(pB, bro[1][0], bro[1][1]);
    i32x8 af0 = ldfrag(pA, aro[0][0], aro[0][1]);
    i32x8 af1 = ldfrag(pA, aro[1][0], aro[1][1]);
    LGKM0;
    BARRIER;                         // all waves' reads done -> buf b reusable
    if (t + 2 < T) stage(t + 2);     // uniform branch
    __builtin_amdgcn_s_setprio(1);
    acc[0][0] = MFMAS(af0, bfv0, acc[0][0]);
    acc[0][1] = MFMAS(af0, bfv1, acc[0][1]);
    acc[1][0] = MFMAS(af1, bfv0, acc[1][0]);
    acc[1][1] = MFMAS(af1, bfv1, acc[1][1]);
    __builtin_amdgcn_s_setprio(0);
    if ((t & 7) == 7) fold(t >> 3);  // nt-tile boundary (uniform)
    if (t + 2 < T) { VMCNT(4); }     // retire tile t+1; t+2 in flight
    else if (t + 1 < T) { VMCNT(0); }
    BARRIER;                         // publish tile t+1
  }

  // writeout: cross-lane min over the 32 cols, 2 lanes (hi) cover distinct row halves
#pragma unroll
  for (int mf = 0; mf < 2; ++mf)
#pragma unroll
    for (int r = 0; r < 16; ++r) {
      unsigned u = rmin2[mf][r >> 1];
      unsigned short us = (r & 1) ? (unsigned short)(u >> 16) : (unsigned short)(u & 0xFFFFu);
      float v = f16bits2f(us);
#pragma unroll
      for (int off = 1; off < 32; off <<= 1) v = fminf(v, __shfl_xor(v, off));
      if (l31 == 0) {
        int row = m0 + wm * 64 + mf * 32 + (r & 3) + 8 * (r >> 2) + 4 * hi;
        minpart[grp * B_SZ + row] = fmaxf(esq[row] + v, 0.0f);
      }
    }
}

// ---------------- final reductions ----------------

__global__ __launch_bounds__(256) void mse_final_k(const float* __restrict__ part,
                                                   float* __restrict__ msev,
                                                   int nparts, float inv_n) {
  float s = 0.f;
  for (int i = threadIdx.x; i < nparts; i += 256) s += part[i];
#pragma unroll
  for (int off = 1; off < 64; off <<= 1) s += __shfl_xor(s, off);
  __shared__ float sm[4];
  if ((threadIdx.x & 63) == 0) sm[threadIdx.x >> 6] = s;
  __syncthreads();
  if (threadIdx.x == 0) msev[0] = (sm[0] + sm[1] + sm[2] + sm[3]) * inv_n;
}

__global__ void finalize_k(const float* __restrict__ minpart,
                           const float* __restrict__ msev,
                           float* __restrict__ out, int n) {
  int i = blockIdx.x * blockDim.x + threadIdx.x;
  if (i < n) {
    float m = 3.0e38f;
#pragma unroll 8
    for (int gp = 0; gp < NGRP; ++gp) m = fminf(m, minpart[gp * B_SZ + i]);
    out[i] = msev[0] + fminf(50.0f - sqrtf(m), 0.0f) * 5.0f;
  }
}

// ---------------- launch ----------------

extern "C" void kernel_launch(void* const* d_in, const int* in_sizes, int n_in,
                              void* d_out, int out_size, void* d_ws, size_t ws_size,
                              hipStream_t stream) {
  const float* x  = (const float*)d_in[0];
  const float* y  = (const float*)d_in[1];
  const float* W  = (const float*)d_in[2];
  const float* lk = (const float*)d_in[3];
  float* out = (float*)d_out;

  char* ws = (char*)d_ws;
  size_t off = 0;
  auto alloc = [&](size_t bytes) -> void* {
    void* p = ws + off;
    off = (off + bytes + 255) & ~(size_t)255;
    return p;
  };
  unsigned char* xa8  = (unsigned char*)alloc((size_t)B_SZ * F_SZ);        // 25.2 MB fp8
  unsigned char* Wt8  = (unsigned char*)alloc((size_t)D_SZ * F_SZ);        // 6.3 MB fp8
  unsigned char* lb   = (unsigned char*)alloc((size_t)N_PAD * D_SZ);       // 51.2 MB fp8
  float* lsq          = (float*)alloc((size_t)N_PAD * 4);
  float* embf         = (float*)alloc((size_t)B_SZ * D_SZ * 4);            // 4 MB
  unsigned char* embq = (unsigned char*)alloc((size_t)B_SZ * D_SZ);        // 1 MB fp8
  float* esq          = (float*)alloc((size_t)B_SZ * 4);
  float* minpart      = (float*)alloc((size_t)NGRP * B_SZ * 4);            // 384 KB
  float* msep         = (float*)alloc(2048 * 4);
  float* msev         = (float*)alloc(256);
  (void)ws_size; (void)in_sizes; (void)n_in; (void)out_size;

  // merged prep (all conversions via hardware cvt_pk_fp8)
  prep_k<<<PREP_TOTAL, 256, 0, stream>>>(x, y, xa8, msep, W, Wt8, lk, lb, lsq, embf);

  // emb(f32) = xa8 @ Wt8^T (x 2^-6) via fp8 split-K=12 atomicAdd
  gemm_a_f8<<<768, 256, 0, stream>>>(xa8, Wt8, embf);
  esq_conv_k<<<B_SZ / 4, 256, 0, stream>>>(embf, embq, esq);

  // persistent fused cdist-min, fp8, 768 blocks (3/CU)
  gemm_min_k<<<768, 256, 0, stream>>>(embq, lb, esq, lsq, minpart);

  mse_final_k<<<1, 256, 0, stream>>>(msep, msev, 2048, 1.0f / ((float)B_SZ * (float)F_SZ));
  finalize_k<<<(B_SZ + 255) / 256, 256, 0, stream>>>(minpart, msev, out, B_SZ);
}

// Round 13
// 253.050 us; speedup vs baseline: 1.9075x; 1.1477x over previous
//
#include <hip/hip_runtime.h>
#include <math.h>

#define B_SZ   2048
#define F_SZ   12288
#define D_SZ   512
#define N_LK   100000
#define N_PAD  100096
#define NT128  782          // N_PAD / 128
#define NGRP   32           // persistent groups (512 blocks = 16 mt x 32 grp, 2/CU)
#define JMAX   25

typedef __attribute__((ext_vector_type(8))) short bf16x8;
typedef __attribute__((ext_vector_type(8))) unsigned short ushort8;
typedef __attribute__((ext_vector_type(4))) float f32x4;
typedef __attribute__((ext_vector_type(16))) float f32x16;
typedef __attribute__((ext_vector_type(8))) int i32x8;

// f32 -> OCP e4m3fn, round-nearest-even (software fallback)
__device__ __forceinline__ unsigned char f2fp8_sw(float f) {
  union { float f; unsigned u; } v; v.f = f;
  unsigned s = (v.u >> 24) & 0x80u;
  unsigned a = v.u & 0x7FFFFFFFu;
  if (a >= 0x43E00000u) return (unsigned char)(s | 0x7E);
  int e32 = (int)(a >> 23) - 127;
  if (e32 < -10) return (unsigned char)s;
  unsigned m24 = (a & 0x7FFFFFu) | 0x800000u;
  int shift = (e32 >= -6) ? 20 : (14 - e32);
  if (shift > 24) return (unsigned char)s;
  unsigned keep = m24 >> shift;
  unsigned rem = m24 & ((1u << shift) - 1u);
  unsigned half = 1u << (shift - 1);
  keep += (rem > half || (rem == half && (keep & 1u))) ? 1u : 0u;
  if (e32 >= -6) {
    if (keep == 16u) { keep = 8u; ++e32; }
    return (unsigned char)(s | ((unsigned)(e32 + 7) << 3) | (keep & 7u));
  }
  if (keep >= 8u) return (unsigned char)(s | 0x08u);
  return (unsigned char)(s | keep);
}

// pack 8 f32 -> 8 fp8 bytes (hardware v_cvt_pk_fp8_f32 when available)
__device__ __forceinline__ uint2 fp8pack8(const float* v) {
#if __has_builtin(__builtin_amdgcn_cvt_pk_fp8_f32)
  int lo = 0, hi = 0;
  lo = __builtin_amdgcn_cvt_pk_fp8_f32(v[0], v[1], lo, false);
  lo = __builtin_amdgcn_cvt_pk_fp8_f32(v[2], v[3], lo, true);
  hi = __builtin_amdgcn_cvt_pk_fp8_f32(v[4], v[5], hi, false);
  hi = __builtin_amdgcn_cvt_pk_fp8_f32(v[6], v[7], hi, true);
  uint2 r; r.x = (unsigned)lo; r.y = (unsigned)hi;
  return r;
#else
  unsigned lo = 0, hi = 0;
#pragma unroll
  for (int j = 0; j < 4; ++j) lo |= (unsigned)f2fp8_sw(v[j]) << (8 * j);
#pragma unroll
  for (int j = 0; j < 4; ++j) hi |= (unsigned)f2fp8_sw(v[j + 4]) << (8 * j);
  uint2 r; r.x = lo; r.y = hi;
  return r;
#endif
}

#define GLOAD16(gp, lp) __builtin_amdgcn_global_load_lds( \
    (__attribute__((address_space(1))) void*)(gp),        \
    (__attribute__((address_space(3))) void*)(lp), 16, 0, 0)

#define VMCNT(n) asm volatile("s_waitcnt vmcnt(" #n ")" ::: "memory")
#define BARRIER __builtin_amdgcn_s_barrier()
#define LGKM0 do { asm volatile("s_waitcnt lgkmcnt(0)" ::: "memory"); \
                   __builtin_amdgcn_sched_barrier(0); } while (0)

// scaled MX MFMA: fmt fp8(e4m3); scale bytes replicated (op_sel-independent)
#define MFMAS(A, B, C) __builtin_amdgcn_mfma_scale_f32_32x32x64_f8f6f4( \
    (A), (B), (C), 0, 0, 0, 0x7F7F7F7F, 0, 0x7F7F7F7F)
// B carries W*64 -> scale_b = 2^-6 (byte 0x79 = 121 -> 2^(121-127))
#define MFMAS_W(A, B, C) __builtin_amdgcn_mfma_scale_f32_32x32x64_f8f6f4( \
    (A), (B), (C), 0, 0, 0, 0x7F7F7F7F, 0, 0x79797979)

__device__ __forceinline__ i32x8 ldfrag(const char* base, int o0, int o1) {
  int4 lo = *(const int4*)(base + o0);
  int4 hi = *(const int4*)(base + o1);
  i32x8 r = {lo.x, lo.y, lo.z, lo.w, hi.x, hi.y, hi.z, hi.w};
  return r;
}

// packed f16 helpers via inline asm (ROCm 7.2 header gaps)
__device__ __forceinline__ unsigned cvt_pkrtz_u32(float a, float b) {
  unsigned r;
  asm volatile("v_cvt_pkrtz_f16_f32 %0, %1, %2" : "=v"(r) : "v"(a), "v"(b));
  return r;
}
__device__ __forceinline__ unsigned pk_min_f16(unsigned a, unsigned b) {
  unsigned r;
  asm volatile("v_pk_min_f16 %0, %1, %2" : "=v"(r) : "v"(a), "v"(b));
  return r;
}
__device__ __forceinline__ float f16bits2f(unsigned short us) {
  float r;
  asm volatile("v_cvt_f32_f16 %0, %1" : "=v"(r) : "v"((unsigned)us));
  return r;
}

// ---------------- merged prep ----------------
#define PREP_MSE_BLKS   2048
#define PREP_TW_BLKS    1536
#define PREP_LK_BLKS    (N_PAD / 4)
#define PREP_ZERO_BLKS  512
#define PREP_TOTAL (PREP_MSE_BLKS + PREP_TW_BLKS + PREP_LK_BLKS + PREP_ZERO_BLKS)

__global__ __launch_bounds__(256) void prep_k(
    const float* __restrict__ x, const float* __restrict__ y,
    unsigned char* __restrict__ xa8, float* __restrict__ part,
    const float* __restrict__ W, unsigned char* __restrict__ Wt8,
    const float* __restrict__ lk, unsigned char* __restrict__ lb,
    float* __restrict__ lsq, float* __restrict__ embf) {
  __shared__ float tl[64][65];
  const int bx = blockIdx.x;
  const int tid = threadIdx.x;

  if (bx < PREP_MSE_BLKS) {
    // ---- x->fp8 + mse partial ----
    const long n8 = (long)B_SZ * F_SZ / 8;
    long i = (long)bx * 256 + tid;
    const long stride = (long)PREP_MSE_BLKS * 256;
    float s = 0.f;
    for (; i < n8; i += stride) {
      const float4* px = (const float4*)(x + i * 8);
      const float4* py = (const float4*)(y + i * 8);
      float4 a = px[0], b = px[1];
      float4 c = py[0], d = py[1];
      float v[8] = {a.x, a.y, a.z, a.w, b.x, b.y, b.z, b.w};
      *(uint2*)(xa8 + i * 8) = fp8pack8(v);
      float t0 = a.x - c.x, t1 = a.y - c.y, t2 = a.z - c.z, t3 = a.w - c.w;
      float t4 = b.x - d.x, t5 = b.y - d.y, t6 = b.z - d.z, t7 = b.w - d.w;
      s += t0 * t0 + t1 * t1 + t2 * t2 + t3 * t3;
      s += t4 * t4 + t5 * t5 + t6 * t6 + t7 * t7;
    }
#pragma unroll
    for (int off = 1; off < 64; off <<= 1) s += __shfl_xor(s, off);
    if ((tid & 63) == 0) tl[0][tid >> 6] = s;
    __syncthreads();
    if (tid == 0) part[bx] = tl[0][0] + tl[0][1] + tl[0][2] + tl[0][3];
  } else if (bx < PREP_MSE_BLKS + PREP_TW_BLKS) {
    // ---- W [F,D] f32 -> Wt8 [D,F] fp8 scaled x64 (e4m3 normal range) ----
    const int b = bx - PREP_MSE_BLKS;
    const int r0 = (b % 192) * 64;  // F dim
    const int c0 = (b / 192) * 64;  // D dim
#pragma unroll
    for (int p = 0; p < 16; ++p) {
      int idx = p * 256 + tid;
      int r = idx >> 6, c = idx & 63;
      tl[c][r] = W[(size_t)(r0 + r) * D_SZ + c0 + c];
    }
    __syncthreads();
#pragma unroll
    for (int p = 0; p < 2; ++p) {
      int chunk = p * 256 + tid;
      int rr = chunk >> 3, cc = (chunk & 7) * 8;
      float v[8];
#pragma unroll
      for (int j = 0; j < 8; ++j) v[j] = tl[rr][cc + j] * 64.0f;
      *(uint2*)&Wt8[(size_t)(c0 + rr) * F_SZ + r0 + cc] = fp8pack8(v);
    }
  } else if (bx < PREP_MSE_BLKS + PREP_TW_BLKS + PREP_LK_BLKS) {
    // ---- lookup f32 -> fp8 (padded) + per-row sumsq (f32); pad sentinel 60000 ----
    const int n = (bx - PREP_MSE_BLKS - PREP_TW_BLKS) * 4 + (tid >> 6);
    const int t = tid & 63;
    uint2 o2 = {0u, 0u};
    float s = 0.f;
    if (n < N_LK) {
      const float4* row = (const float4*)(lk + (size_t)n * D_SZ);
      float4 a = row[t * 2], b = row[t * 2 + 1];
      float v[8] = {a.x, a.y, a.z, a.w, b.x, b.y, b.z, b.w};
      o2 = fp8pack8(v);
#pragma unroll
      for (int j = 0; j < 8; ++j) s += v[j] * v[j];
    }
    *(uint2*)&lb[(size_t)n * D_SZ + t * 8] = o2;
#pragma unroll
    for (int off = 1; off < 64; off <<= 1) s += __shfl_xor(s, off);
    if (t == 0) lsq[n] = (n < N_LK) ? s : 60000.0f;
  } else {
    long i = (long)(bx - PREP_MSE_BLKS - PREP_TW_BLKS - PREP_LK_BLKS) * 256 + tid;
    const long n4 = (long)B_SZ * D_SZ / 4;
    const long stride = (long)PREP_ZERO_BLKS * 256;
    float4 z = {0.f, 0.f, 0.f, 0.f};
    for (; i < n4; i += stride) ((float4*)embf)[i] = z;
  }
}

// ---------------- GEMM-A fp8 split-K=12 (R12, verified) ----------------
__global__ __launch_bounds__(256, 3) void gemm_a_f8(
    const unsigned char* __restrict__ Aq,   // xa8 [2048][12288] fp8
    const unsigned char* __restrict__ Bq,   // Wt8 [512][12288] fp8 (x64)
    float* __restrict__ embf) {
  __shared__ char lsA[2 * 8192];
  __shared__ char lsB[2 * 8192];
  const int tid = threadIdx.x;
  const int bid = blockIdx.x;
  const int mt = bid & 15, dt = (bid >> 4) & 3, ks = bid >> 6;
  const int m0 = mt * 128, n0 = dt * 128;
  const size_t kbase = (size_t)ks * 1024;

  const int l = tid & 63;
  const int wid = tid >> 6;
  const int wm = wid >> 1, wn = wid & 1;
  const int hi = l >> 5, l31 = l & 31;

  const int srow = tid >> 2;
  const int sslot = (tid & 3) ^ ((tid >> 3) & 3);
  const unsigned char* Abase = Aq + (size_t)(m0 + srow) * F_SZ + kbase + sslot * 16;
  const unsigned char* Bbase = Bq + (size_t)(n0 + srow) * F_SZ + kbase + sslot * 16;

  int aro[2][2], bro[2][2];
#pragma unroll
  for (int mf = 0; mf < 2; ++mf) {
    int row = wm * 64 + mf * 32 + l31;
#pragma unroll
    for (int j = 0; j < 2; ++j)
      aro[mf][j] = row * 64 + (((hi * 2 + j) ^ ((l31 >> 1) & 3)) << 4);
  }
#pragma unroll
  for (int nf = 0; nf < 2; ++nf) {
    int row = wn * 64 + nf * 32 + l31;
#pragma unroll
    for (int j = 0; j < 2; ++j)
      bro[nf][j] = row * 64 + (((hi * 2 + j) ^ ((l31 >> 1) & 3)) << 4);
  }

  f32x16 acc[2][2] = {};

  auto stage = [&](int s) {
    const int b = s & 1;
    const int koff = s * 64;
    GLOAD16(Abase + koff, lsA + b * 8192 + tid * 16);
    GLOAD16(Abase + (size_t)64 * F_SZ + koff, lsA + b * 8192 + 4096 + tid * 16);
    GLOAD16(Bbase + koff, lsB + b * 8192 + tid * 16);
    GLOAD16(Bbase + (size_t)64 * F_SZ + koff, lsB + b * 8192 + 4096 + tid * 16);
  };

  stage(0); stage(1);
  VMCNT(4);
  BARRIER;

  for (int t = 0; t < 16; ++t) {
    const int b = t & 1;
    const char* pA = lsA + b * 8192;
    const char* pB = lsB + b * 8192;
    i32x8 bfv0 = ldfrag(pB, bro[0][0], bro[0][1]);
    i32x8 bfv1 = ldfrag(pB, bro[1][0], bro[1][1]);
    i32x8 af0 = ldfrag(pA, aro[0][0], aro[0][1]);
    i32x8 af1 = ldfrag(pA, aro[1][0], aro[1][1]);
    LGKM0;
    BARRIER;
    if (t + 2 < 16) stage(t + 2);
    __builtin_amdgcn_s_setprio(1);
    acc[0][0] = MFMAS_W(af0, bfv0, acc[0][0]);
    acc[0][1] = MFMAS_W(af0, bfv1, acc[0][1]);
    acc[1][0] = MFMAS_W(af1, bfv0, acc[1][0]);
    acc[1][1] = MFMAS_W(af1, bfv1, acc[1][1]);
    __builtin_amdgcn_s_setprio(0);
    if (t + 2 < 16) { VMCNT(4); }
    else if (t + 1 < 16) { VMCNT(0); }
    BARRIER;
  }

  // epilogue: C/D 32x32 layout row=(r&3)+8*(r>>2)+4*hi, col=l31
#pragma unroll
  for (int mf = 0; mf < 2; ++mf)
#pragma unroll
    for (int nf = 0; nf < 2; ++nf)
#pragma unroll
      for (int r = 0; r < 16; ++r) {
        int row = m0 + wm * 64 + mf * 32 + (r & 3) + 8 * (r >> 2) + 4 * hi;
        int col = n0 + wn * 64 + nf * 32 + l31;
        atomicAdd(&embf[(size_t)row * D_SZ + col], acc[mf][nf][r]);
      }
}

// embf f32 -> embq fp8 + per-row esq (f32)
__global__ __launch_bounds__(256) void esq_conv_k(const float* __restrict__ embf,
                                                  unsigned char* __restrict__ embq,
                                                  float* __restrict__ esq) {
  int r = blockIdx.x * 4 + (threadIdx.x >> 6);
  int t = threadIdx.x & 63;
  const float4* row = (const float4*)(embf + (size_t)r * D_SZ);
  float4 a = row[t * 2], b = row[t * 2 + 1];
  float v[8] = {a.x, a.y, a.z, a.w, b.x, b.y, b.z, b.w};
  float s = 0.f;
#pragma unroll
  for (int j = 0; j < 8; ++j) s += v[j] * v[j];
  *(uint2*)&embq[(size_t)r * D_SZ + t * 8] = fp8pack8(v);
#pragma unroll
  for (int off = 1; off < 64; off <<= 1) s += __shfl_xor(s, off);
  if (t == 0) esq[r] = s;
}

// ---------------- GEMM-B: persistent fused cdist-min, fp8, A-in-registers ----------
// 512 blocks (2/CU), 128x128 tile, 4 waves 2x2. A (embq, 1MB L2-resident, nt-invariant)
// lives ENTIRELY in registers: per lane 8 ksteps x 2 mf x 32B = 128 VGPR, loaded once.
// LDS holds only the B ring (2 x 8KB) -> per-step LDS traffic halves vs R12.
// K-loop = for j { unrolled ks=0..7 } so all areg indices are compile-time (rule #20).
// Counted vmcnt(2): B stages 2 loads/tile; A-loads drained (vmcnt0+sched_barrier) before
// the pipeline baseline so the accounting stays exact. Fold = packed-f16 register min.
__global__ __launch_bounds__(256, 2) void gemm_min_k(
    const unsigned char* __restrict__ Aq,   // embq [2048][512] fp8
    const unsigned char* __restrict__ Bq,   // lb   [100096][512] fp8
    const float* __restrict__ esq, const float* __restrict__ lsq,
    float* __restrict__ minpart) {          // [NGRP][2048]
  __shared__ char lsB[2 * 8192];
  __shared__ float lsq_lds[JMAX * 128];

  const int tid = threadIdx.x;
  const int grp = blockIdx.x % NGRP;
  const int mt = blockIdx.x / NGRP;     // 0..15
  const int m0 = mt * 128;
  const int J = (NT128 - grp + NGRP - 1) / NGRP;  // 24 or 25

  const int l = tid & 63;
  const int wid = tid >> 6;
  const int wm = wid >> 1, wn = wid & 1;          // 2x2 waves, tile 64x64
  const int hi = l >> 5, l31 = l & 31;

  // B staging: linear LDS dest; source 16B slot pre-swizzled (slot' = slot^((row>>1)&3))
  const int srow = tid >> 2;                      // 0..63 (per half)
  const int sslot = (tid & 3) ^ ((tid >> 3) & 3);
  const unsigned char* Bbase = Bq + (size_t)srow * D_SZ + sslot * 16;

  int bro[2][2];
#pragma unroll
  for (int nf = 0; nf < 2; ++nf) {
    int row = wn * 64 + nf * 32 + l31;
#pragma unroll
    for (int j = 0; j < 2; ++j)
      bro[nf][j] = row * 64 + (((hi * 2 + j) ^ ((l31 >> 1) & 3)) << 4);
  }

  // lsq -> LDS (plain global loads, drained below)
  for (int j = 0; j < J; ++j)
    if (tid < 128) lsq_lds[j * 128 + tid] = lsq[(grp + NGRP * j) * 128 + tid];

  // A -> registers: lane holds rows (wm*64 + mf*32 + l31), k [ks*64+hi*32, +32)
  i32x8 areg[8][2];
  {
    const unsigned char* Arow = Aq + (size_t)(m0 + wm * 64 + l31) * D_SZ + hi * 32;
#pragma unroll
    for (int ks = 0; ks < 8; ++ks)
#pragma unroll
      for (int mf = 0; mf < 2; ++mf) {
        const int4* p = (const int4*)(Arow + (size_t)mf * 32 * D_SZ + ks * 64);
        int4 lo = p[0], hi4 = p[1];
        areg[ks][mf] = i32x8{lo.x, lo.y, lo.z, lo.w, hi4.x, hi4.y, hi4.z, hi4.w};
      }
  }
  VMCNT(0);                             // drain A/lsq loads -> clean vmcnt baseline
  __builtin_amdgcn_sched_barrier(0);
  __syncthreads();

  f32x16 acc[2][2] = {};
  const f32x16 fzero = {};
  unsigned rmin2[2][8];
#pragma unroll
  for (int mf = 0; mf < 2; ++mf)
#pragma unroll
    for (int q = 0; q < 8; ++q) rmin2[mf][q] = 0x7BFF7BFFu;  // +65504 packed f16 x2

  auto stageB = [&](size_t boff, int koff, int b) {
    GLOAD16(Bbase + boff + koff, lsB + b * 8192 + tid * 16);
    GLOAD16(Bbase + boff + (size_t)64 * D_SZ + koff, lsB + b * 8192 + 4096 + tid * 16);
  };
  auto fold = [&](int j) {
    const float lq0 = lsq_lds[j * 128 + wn * 64 + l31];
    const float lq1 = lsq_lds[j * 128 + wn * 64 + 32 + l31];
#pragma unroll
    for (int mf = 0; mf < 2; ++mf) {
#pragma unroll
      for (int q = 0; q < 8; ++q) {
        float v0 = fminf(fmaf(-2.f, acc[mf][0][2 * q], lq0),
                         fmaf(-2.f, acc[mf][1][2 * q], lq1));
        float v1 = fminf(fmaf(-2.f, acc[mf][0][2 * q + 1], lq0),
                         fmaf(-2.f, acc[mf][1][2 * q + 1], lq1));
        rmin2[mf][q] = pk_min_f16(rmin2[mf][q], cvt_pkrtz_u32(v0, v1));
      }
      acc[mf][0] = fzero;
      acc[mf][1] = fzero;
    }
  };

  const size_t BSTRIDE = (size_t)NGRP * 128 * D_SZ;

  // prologue: tiles (k-steps) 0,1 in flight; retire step 0
  {
    const size_t boff0 = (size_t)grp * 128 * D_SZ;
    stageB(boff0, 0, 0);
    stageB(boff0, 64, 1);
  }
  VMCNT(2);
  BARRIER;

  for (int j = 0; j < J; ++j) {
    const size_t boff0 = (size_t)grp * 128 * D_SZ + (size_t)j * BSTRIDE;
    const size_t boff1 = boff0 + BSTRIDE;
    const bool lastj = (j == J - 1);
#pragma unroll
    for (int ks = 0; ks < 8; ++ks) {
      const int b = ks & 1;
      const char* pB = lsB + b * 8192;
      i32x8 bfv0 = ldfrag(pB, bro[0][0], bro[0][1]);
      i32x8 bfv1 = ldfrag(pB, bro[1][0], bro[1][1]);
      LGKM0;
      BARRIER;                          // all waves' reads done -> buf b reusable
      if (ks < 6) {
        stageB(boff0, (ks + 2) * 64, b);            // step t+2 -> same parity buf
      } else if (!lastj) {
        stageB(boff1, (ks - 6) * 64, b);            // next nt-tile, steps 0/1
      }
      __builtin_amdgcn_s_setprio(1);
      acc[0][0] = MFMAS(areg[ks][0], bfv0, acc[0][0]);
      acc[0][1] = MFMAS(areg[ks][0], bfv1, acc[0][1]);
      acc[1][0] = MFMAS(areg[ks][1], bfv0, acc[1][0]);
      acc[1][1] = MFMAS(areg[ks][1], bfv1, acc[1][1]);
      __builtin_amdgcn_s_setprio(0);
      if (ks == 7) fold(j);             // nt-tile boundary (uniform)
      if (ks < 6) { VMCNT(2); }         // retire step t+1; t+2 in flight
      else if (!lastj) { VMCNT(2); }
      else if (ks == 6) { VMCNT(0); }   // last tile: drain final step
      BARRIER;                          // publish step t+1
    }
  }

  // writeout: cross-lane min over the 32 cols, 2 lanes (hi) cover distinct row halves
#pragma unroll
  for (int mf = 0; mf < 2; ++mf)
#pragma unroll
    for (int r = 0; r < 16; ++r) {
      unsigned u = rmin2[mf][r >> 1];
      unsigned short us = (r & 1) ? (unsigned short)(u >> 16) : (unsigned short)(u & 0xFFFFu);
      float v = f16bits2f(us);
#pragma unroll
      for (int off = 1; off < 32; off <<= 1) v = fminf(v, __shfl_xor(v, off));
      if (l31 == 0) {
        int row = m0 + wm * 64 + mf * 32 + (r & 3) + 8 * (r >> 2) + 4 * hi;
        minpart[grp * B_SZ + row] = fmaxf(esq[row] + v, 0.0f);
      }
    }
}

// ---------------- final reductions ----------------

__global__ __launch_bounds__(256) void mse_final_k(const float* __restrict__ part,
                                                   float* __restrict__ msev,
                                                   int nparts, float inv_n) {
  float s = 0.f;
  for (int i = threadIdx.x; i < nparts; i += 256) s += part[i];
#pragma unroll
  for (int off = 1; off < 64; off <<= 1) s += __shfl_xor(s, off);
  __shared__ float sm[4];
  if ((threadIdx.x & 63) == 0) sm[threadIdx.x >> 6] = s;
  __syncthreads();
  if (threadIdx.x == 0) msev[0] = (sm[0] + sm[1] + sm[2] + sm[3]) * inv_n;
}

__global__ void finalize_k(const float* __restrict__ minpart,
                           const float* __restrict__ msev,
                           float* __restrict__ out, int n) {
  int i = blockIdx.x * blockDim.x + threadIdx.x;
  if (i < n) {
    float m = 3.0e38f;
#pragma unroll 8
    for (int gp = 0; gp < NGRP; ++gp) m = fminf(m, minpart[gp * B_SZ + i]);
    out[i] = msev[0] + fminf(50.0f - sqrtf(m), 0.0f) * 5.0f;
  }
}

// ---------------- launch ----------------

extern "C" void kernel_launch(void* const* d_in, const int* in_sizes, int n_in,
                              void* d_out, int out_size, void* d_ws, size_t ws_size,
                              hipStream_t stream) {
  const float* x  = (const float*)d_in[0];
  const float* y  = (const float*)d_in[1];
  const float* W  = (const float*)d_in[2];
  const float* lk = (const float*)d_in[3];
  float* out = (float*)d_out;

  char* ws = (char*)d_ws;
  size_t off = 0;
  auto alloc = [&](size_t bytes) -> void* {
    void* p = ws + off;
    off = (off + bytes + 255) & ~(size_t)255;
    return p;
  };
  unsigned char* xa8  = (unsigned char*)alloc((size_t)B_SZ * F_SZ);        // 25.2 MB fp8
  unsigned char* Wt8  = (unsigned char*)alloc((size_t)D_SZ * F_SZ);        // 6.3 MB fp8
  unsigned char* lb   = (unsigned char*)alloc((size_t)N_PAD * D_SZ);       // 51.2 MB fp8
  float* lsq          = (float*)alloc((size_t)N_PAD * 4);
  float* embf         = (float*)alloc((size_t)B_SZ * D_SZ * 4);            // 4 MB
  unsigned char* embq = (unsigned char*)alloc((size_t)B_SZ * D_SZ);        // 1 MB fp8
  float* esq          = (float*)alloc((size_t)B_SZ * 4);
  float* minpart      = (float*)alloc((size_t)NGRP * B_SZ * 4);            // 256 KB
  float* msep         = (float*)alloc(2048 * 4);
  float* msev         = (float*)alloc(256);
  (void)ws_size; (void)in_sizes; (void)n_in; (void)out_size;

  // merged prep (all conversions via hardware cvt_pk_fp8)
  prep_k<<<PREP_TOTAL, 256, 0, stream>>>(x, y, xa8, msep, W, Wt8, lk, lb, lsq, embf);

  // emb(f32) = xa8 @ Wt8^T (x 2^-6) via fp8 split-K=12 atomicAdd
  gemm_a_f8<<<768, 256, 0, stream>>>(xa8, Wt8, embf);
  esq_conv_k<<<B_SZ / 4, 256, 0, stream>>>(embf, embq, esq);

  // persistent fused cdist-min, fp8, A-in-registers, 512 blocks (2/CU)
  gemm_min_k<<<512, 256, 0, stream>>>(embq, lb, esq, lsq, minpart);

  mse_final_k<<<1, 256, 0, stream>>>(msep, msev, 2048, 1.0f / ((float)B_SZ * (float)F_SZ));
  finalize_k<<<(B_SZ + 255) / 256, 256, 0, stream>>>(minpart, msev, out, B_SZ);
}